// Round 2
// baseline (1483.313 us; speedup 1.0000x reference)
//
#include <hip/hip_runtime.h>
#include <hip/hip_bf16.h>
#include <cstdint>
#include <cstddef>

typedef unsigned short u16;
typedef float f32x4 __attribute__((ext_vector_type(4)));
typedef short bf16x8 __attribute__((ext_vector_type(8)));
typedef unsigned short u16x8 __attribute__((ext_vector_type(8)));

__device__ __forceinline__ u16 f2bf(float f) {
    uint32_t u = __float_as_uint(f);
    u += 0x7fffu + ((u >> 16) & 1u);
    return (u16)(u >> 16);
}
__device__ __forceinline__ float bf2f(u16 h) {
    return __uint_as_float(((uint32_t)h) << 16);
}

// ---------------- W pre-transpose + swizzle: Wt[c*512 + (k ^ ((c&7)<<3))] = bf16(W[k*64+c])
__global__ __launch_bounds__(256) void k_prep(const float* __restrict__ Wg, u16* __restrict__ Wt) {
    int idx = blockIdx.x * 256 + threadIdx.x;   // 32768
    int k = idx >> 6, c = idx & 63;
    int lin = c * 512 + (k ^ ((c & 7) << 3));
    Wt[lin] = f2bf(Wg[idx]);
}

// ---------------- degrees + histogram + m   (edges are int32 per harness ABI!)
__global__ __launch_bounds__(256) void k_deg(const int* __restrict__ esrc,
    const int* __restrict__ edst, const float* __restrict__ ev, const int E,
    float* __restrict__ deg_row, float* __restrict__ deg_col, int* __restrict__ cnt,
    float* __restrict__ scal) {
    const int gid = blockIdx.x * 256 + threadIdx.x;
    const int stride = gridDim.x * 256;
    float vsum = 0.f;
    for (int e = gid; e < E; e += stride) {
        const int s = esrc[e], t = edst[e];
        const float v = ev[e];
        atomicAdd(deg_row + s, v);
        atomicAdd(deg_col + t, v);
        atomicAdd(cnt + s, 1);
        vsum += v;
    }
    #pragma unroll
    for (int mm = 1; mm < 64; mm <<= 1) vsum += __shfl_xor(vsum, mm);
    if ((threadIdx.x & 63) == 0) atomicAdd(scal + 0, vsum);
}

// ---------------- fused logits GEMM + softmax  (BM=64, 4 waves x 16 rows, full N=64)
__global__ __launch_bounds__(256) void k1(const float* __restrict__ F,
    const u16* __restrict__ WtG, const float* __restrict__ bias,
    float* __restrict__ S_out, u16* __restrict__ Sbf,
    float* __restrict__ sizes, float* __restrict__ scal) {
    __shared__ __align__(16) u16 Wl[64 * 512];
    __shared__ __align__(16) u16 Al[64 * 64];
    __shared__ float red4[4];
    const int tid = threadIdx.x;
    const int row0 = blockIdx.x * 64;
    for (int j = tid; j < 4096; j += 256)
        ((uint4*)Wl)[j] = ((const uint4*)WtG)[j];

    const int lane = tid & 63;
    const int wv = __builtin_amdgcn_readfirstlane(tid >> 6);
    const int l15 = lane & 15, lq = lane >> 4;
    f32x4 acc[4];
    #pragma unroll
    for (int tn = 0; tn < 4; tn++)
        #pragma unroll
        for (int e = 0; e < 4; e++) acc[tn][e] = 0.f;
    float sumf2 = 0.f;
    const int sr = tid >> 2, skq = tid & 3;
    const int sw = (sr & 7) << 3;

    for (int k0 = 0; k0 < 512; k0 += 64) {
        const float* fp = F + (size_t)(row0 + sr) * 512 + k0 + skq * 16;
        float4 v[4];
        u16 h[16];
        #pragma unroll
        for (int q = 0; q < 4; q++) v[q] = ((const float4*)fp)[q];
        #pragma unroll
        for (int q = 0; q < 4; q++) {
            sumf2 += v[q].x * v[q].x + v[q].y * v[q].y + v[q].z * v[q].z + v[q].w * v[q].w;
            h[q * 4 + 0] = f2bf(v[q].x); h[q * 4 + 1] = f2bf(v[q].y);
            h[q * 4 + 2] = f2bf(v[q].z); h[q * 4 + 3] = f2bf(v[q].w);
        }
        #pragma unroll
        for (int half = 0; half < 2; half++) {
            u16x8 pk;
            #pragma unroll
            for (int e2 = 0; e2 < 8; e2++) pk[e2] = h[half * 8 + e2];
            *(u16x8*)&Al[sr * 64 + ((skq * 16 + half * 8) ^ sw)] = pk;
        }
        __syncthreads();
        #pragma unroll
        for (int kk = 0; kk < 64; kk += 32) {
            const int arow = wv * 16 + l15;
            bf16x8 a = *(const bf16x8*)&Al[arow * 64 + ((kk + lq * 8) ^ ((arow & 7) << 3))];
            #pragma unroll
            for (int tn = 0; tn < 4; tn++) {
                const int bc = tn * 16 + l15;
                bf16x8 b = *(const bf16x8*)&Wl[bc * 512 + ((k0 + kk + lq * 8) ^ ((bc & 7) << 3))];
                acc[tn] = __builtin_amdgcn_mfma_f32_16x16x32_bf16(a, b, acc[tn], 0, 0, 0);
            }
        }
        __syncthreads();
    }

    // softmax epilogue: lane holds rows (lq*4+r), cols (l15 + 16*tn)
    float bias4[4], szacc[4] = {0.f, 0.f, 0.f, 0.f};
    #pragma unroll
    for (int tn = 0; tn < 4; tn++) bias4[tn] = bias[tn * 16 + l15];
    #pragma unroll
    for (int r2 = 0; r2 < 4; r2++) {
        float L[4];
        #pragma unroll
        for (int tn = 0; tn < 4; tn++) L[tn] = acc[tn][r2] + bias4[tn];
        float mx = fmaxf(fmaxf(L[0], L[1]), fmaxf(L[2], L[3]));
        #pragma unroll
        for (int mm = 1; mm < 16; mm <<= 1) mx = fmaxf(mx, __shfl_xor(mx, mm));
        float e[4], s = 0.f;
        #pragma unroll
        for (int tn = 0; tn < 4; tn++) { e[tn] = __expf(L[tn] - mx); s += e[tn]; }
        #pragma unroll
        for (int mm = 1; mm < 16; mm <<= 1) s += __shfl_xor(s, mm);
        const float inv = 1.f / s;
        const size_t grow = (size_t)(row0 + wv * 16 + lq * 4 + r2);
        #pragma unroll
        for (int tn = 0; tn < 4; tn++) {
            const float svl = e[tn] * inv;
            S_out[grow * 64 + tn * 16 + l15] = svl;
            Sbf[grow * 64 + tn * 16 + l15] = f2bf(svl);
            szacc[tn] += svl;
        }
    }
    #pragma unroll
    for (int tn = 0; tn < 4; tn++) {
        float vs = szacc[tn];
        vs += __shfl_xor(vs, 16);
        vs += __shfl_xor(vs, 32);
        if (lq == 0) atomicAdd(sizes + tn * 16 + l15, vs);
    }
    #pragma unroll
    for (int mm = 1; mm < 64; mm <<= 1) sumf2 += __shfl_xor(sumf2, mm);
    if (lane == 0) red4[wv] = sumf2;
    __syncthreads();
    if (tid == 0) atomicAdd(scal + 1, red4[0] + red4[1] + red4[2] + red4[3]);
}

// ---------------- exclusive scan of cnt -> row_start, cursor (single block)
__global__ __launch_bounds__(1024) void k_scan(const int* __restrict__ cnt,
    int* __restrict__ row_start, int* __restrict__ cursor, const int n) {
    __shared__ int lds[1024];
    const int t = threadIdx.x;
    const int per = n >> 10;
    const int base = t * per;
    int s = 0;
    for (int j = 0; j < per; j++) s += cnt[base + j];
    lds[t] = s;
    __syncthreads();
    for (int off = 1; off < 1024; off <<= 1) {
        int v = (t >= off) ? lds[t - off] : 0;
        __syncthreads();
        lds[t] += v;
        __syncthreads();
    }
    int run = lds[t] - s;
    for (int j = 0; j < per; j++) {
        const int idx = base + j;
        row_start[idx] = run;
        cursor[idx] = run;
        run += cnt[idx];
    }
    if (t == 1023) row_start[n] = run;
}

// ---------------- counting-sort scatter  (edges int32)
__global__ __launch_bounds__(256) void k_scatter(const int* __restrict__ esrc,
    const int* __restrict__ edst, const float* __restrict__ ev, const int E,
    int* __restrict__ cursor, int2* __restrict__ sedge) {
    const int gid = blockIdx.x * 256 + threadIdx.x;
    const int stride = gridDim.x * 256;
    for (int e = gid; e < E; e += stride) {
        const int s = esrc[e];
        const int pos = atomicAdd(cursor + s, 1);
        sedge[pos] = make_int2(edst[e], __float_as_int(ev[e]));
    }
}

// ---------------- G = S^T F  (f32 S, split-K, LDS-combined atomics)
__global__ __launch_bounds__(256) void k2(const float* __restrict__ F,
    const float* __restrict__ S, float* __restrict__ G) {
    __shared__ float Gl[4][64][64];
    const int tid = threadIdx.x, lane = tid & 63;
    const int wv = __builtin_amdgcn_readfirstlane(tid >> 6);
    const int d0 = (blockIdx.x & 7) * 64;
    const int rbase = (blockIdx.x >> 3) * 1024 + wv * 256;
    float acc[64];
    #pragma unroll
    for (int j = 0; j < 64; j++) acc[j] = 0.f;
    for (int r = 0; r < 256; r++) {
        const int i = rbase + r;
        const float sv = S[(size_t)i * 64 + lane];
        const float* fr = F + (size_t)i * 512 + d0;
        #pragma unroll
        for (int j = 0; j < 64; j++) acc[j] = fmaf(fr[j], sv, acc[j]);
    }
    #pragma unroll
    for (int j = 0; j < 64; j++) Gl[wv][lane][j] = acc[j];
    __syncthreads();
    #pragma unroll 4
    for (int q = 0; q < 16; q++) {
        const int cell = tid * 16 + q, c = cell >> 6, j = cell & 63;
        atomicAdd(G + (size_t)c * 512 + d0 + j,
                  Gl[0][c][j] + Gl[1][c][j] + Gl[2][c][j] + Gl[3][c][j]);
    }
}

// ---------------- AS rows (bf16), wave per row, lane = cluster
__global__ __launch_bounds__(256) void k_as(const int* __restrict__ row_start,
    const int2* __restrict__ sedge, const u16* __restrict__ Sbf, u16* __restrict__ ASbf) {
    const int lane = threadIdx.x & 63;
    const int wv = __builtin_amdgcn_readfirstlane((int)(threadIdx.x >> 6));
    const int i = blockIdx.x * 4 + wv;
    const int e0 = row_start[i], e1 = row_start[i + 1];
    float acc = 0.f;
    for (int e = e0; e < e1; e++) {
        const int2 p = sedge[e];
        acc = fmaf(__int_as_float(p.y), bf2f(Sbf[(size_t)p.x * 64 + lane]), acc);
    }
    ASbf[(size_t)i * 64 + lane] = f2bf(acc);
}

// ---------------- exact f32 AS rows 0..63 (trace_loss path)
__global__ __launch_bounds__(64) void k_as64(const int* __restrict__ row_start,
    const int2* __restrict__ sedge, const float* __restrict__ S, float* __restrict__ AS64) {
    const int lane = threadIdx.x;
    const int i = blockIdx.x;
    const int e0 = row_start[i], e1 = row_start[i + 1];
    float acc = 0.f;
    for (int e = e0; e < e1; e++) {
        const int2 p = sedge[e];
        acc = fmaf(__int_as_float(p.y), S[(size_t)p.x * 64 + lane], acc);
    }
    AS64[i * 64 + lane] = acc;
}

// ---------------- fused k x k reductions: GP=AS^T S, SS=S^T S, SDS=(deg.S)^T S, u=S^T deg_col
__global__ __launch_bounds__(256) void k_kk(const u16* __restrict__ Sbf,
    const u16* __restrict__ ASbf, const float* __restrict__ deg_row,
    const float* __restrict__ deg_col, float* __restrict__ GP, float* __restrict__ SS,
    float* __restrict__ SDS, float* __restrict__ u_vec) {
    __shared__ float Pgp[4][16][64];
    __shared__ float Pss[4][16][64];
    __shared__ float Psds[4][16][64];
    __shared__ float Pu[4][64];
    const int tid = threadIdx.x, lane = tid & 63;
    const int wv = __builtin_amdgcn_readfirstlane(tid >> 6);
    const int cs = blockIdx.x & 3, c0 = cs * 16;
    const int rbase = (blockIdx.x >> 2) * 512 + wv * 128;
    float gp[16], ss[16], sds[16], ua = 0.f;
    #pragma unroll
    for (int cc = 0; cc < 16; cc++) { gp[cc] = 0.f; ss[cc] = 0.f; sds[cc] = 0.f; }
    for (int r = 0; r < 128; r++) {
        const int i = rbase + r;
        const float sv = bf2f(Sbf[(size_t)i * 64 + lane]);
        const float dr = deg_row[i];
        ua = fmaf(deg_col[i], sv, ua);
        const u16* srow = Sbf + (size_t)i * 64 + c0;
        const u16* arow = ASbf + (size_t)i * 64 + c0;
        #pragma unroll
        for (int cc = 0; cc < 16; cc++) {
            const float sc = bf2f(srow[cc]);
            const float ac = bf2f(arow[cc]);
            ss[cc] = fmaf(sc, sv, ss[cc]);
            sds[cc] = fmaf(sc * dr, sv, sds[cc]);
            gp[cc] = fmaf(ac, sv, gp[cc]);
        }
    }
    #pragma unroll
    for (int cc = 0; cc < 16; cc++) {
        Pgp[wv][cc][lane] = gp[cc]; Pss[wv][cc][lane] = ss[cc]; Psds[wv][cc][lane] = sds[cc];
    }
    Pu[wv][lane] = ua;
    __syncthreads();
    for (int q = 0; q < 4; q++) {
        const int cell = tid * 4 + q, cc = cell >> 6, l = cell & 63;
        atomicAdd(GP + (c0 + cc) * 64 + l, Pgp[0][cc][l] + Pgp[1][cc][l] + Pgp[2][cc][l] + Pgp[3][cc][l]);
        atomicAdd(SS + (c0 + cc) * 64 + l, Pss[0][cc][l] + Pss[1][cc][l] + Pss[2][cc][l] + Pss[3][cc][l]);
        atomicAdd(SDS + (c0 + cc) * 64 + l, Psds[0][cc][l] + Psds[1][cc][l] + Psds[2][cc][l] + Psds[3][cc][l]);
    }
    if (cs == 0 && tid < 64)
        atomicAdd(u_vec + tid, Pu[0][tid] + Pu[1][tid] + Pu[2][tid] + Pu[3][tid]);
}

__device__ __forceinline__ float bred256(float v, float* red) {
    #pragma unroll
    for (int mm = 1; mm < 64; mm <<= 1) v += __shfl_xor(v, mm);
    const int t = threadIdx.x;
    __syncthreads();
    if ((t & 63) == 0) red[t >> 6] = v;
    __syncthreads();
    return red[0] + red[1] + red[2] + red[3];
}

// ---------------- FP = selu(G/sizes) + <G,FP>
__global__ __launch_bounds__(256) void k_fp(const float* __restrict__ G,
    const float* __restrict__ sizes, float* __restrict__ FP, float* __restrict__ scal) {
    __shared__ float red[4];
    const int idx = blockIdx.x * 256 + threadIdx.x;
    const int c = idx >> 9;
    const float g = G[idx];
    const float x = g / sizes[c];
    const float fp = 1.0507009873554805f * (x > 0.f ? x : 1.6732632423543772f * (__expf(x) - 1.f));
    FP[idx] = fp;
    const float gd = bred256(g * fp, red);
    if (threadIdx.x == 0) atomicAdd(scal + 2, gd);
}

// ---------------- FFt = FP FP^T
__global__ __launch_bounds__(256) void k_fft(const float* __restrict__ FP, float* __restrict__ FFt) {
    __shared__ float red[256];
    const int c = blockIdx.x;
    const int cp = threadIdx.x & 63, part = threadIdx.x >> 6;
    float a = 0.f;
    const int dbase = part * 128;
    for (int dd = 0; dd < 128; dd++)
        a = fmaf(FP[c * 512 + dbase + dd], FP[cp * 512 + dbase + dd], a);
    red[threadIdx.x] = a;
    __syncthreads();
    if (threadIdx.x < 64)
        FFt[c * 64 + threadIdx.x] = red[threadIdx.x] + red[threadIdx.x + 64] +
                                    red[threadIdx.x + 128] + red[threadIdx.x + 192];
}

// ---------------- logabsdet(StLS + 1) via LU w/ partial pivoting (1 wave)
__global__ __launch_bounds__(64) void k_lu(const float* __restrict__ SDS,
    const float* __restrict__ GP, float* __restrict__ scal) {
    __shared__ float M[64][65];
    const int l = threadIdx.x;
    for (int c = 0; c < 64; c++) M[l][c] = SDS[l * 64 + c] - GP[l * 64 + c] + 1.0f;
    __syncthreads();
    float logdet = 0.f;
    for (int k = 0; k < 64; k++) {
        float v = (l >= k) ? fabsf(M[l][k]) : -1.f;
        int idx = l;
        #pragma unroll
        for (int mm = 1; mm < 64; mm <<= 1) {
            const float ov = __shfl_xor(v, mm);
            const int oi = __shfl_xor(idx, mm);
            if (ov > v || (ov == v && oi < idx)) { v = ov; idx = oi; }
        }
        if (idx != k) {
            const float t1 = M[k][l], t2 = M[idx][l];
            __syncthreads();
            M[k][l] = t2;
            M[idx][l] = t1;
        }
        __syncthreads();
        const float piv = M[k][k];
        logdet += logf(fabsf(piv));
        if (l > k) {
            const float f = M[l][k] / piv;
            for (int c = k + 1; c < 64; c++) M[l][c] = fmaf(-f, M[k][c], M[l][c]);
        }
        __syncthreads();
    }
    if (l == 0) scal[3] = logdet;
}

// ---------------- final loss assembly
__global__ __launch_bounds__(256) void k_final(const float* __restrict__ GP,
    const float* __restrict__ SS, const float* __restrict__ FFt, const float* __restrict__ u_vec,
    const float* __restrict__ sizes, const float* __restrict__ deg_row,
    const float* __restrict__ AS64, const float* __restrict__ S,
    const float* __restrict__ scal, float* __restrict__ out_loss, const float fn) {
    __shared__ float red[4];
    const int t = threadIdx.x;
    float sA = 0.f, trl = 0.f, trg = 0.f, u2 = 0.f, sz2 = 0.f;
    for (int q = t; q < 4096; q += 256) sA += SS[q] * FFt[q];
    for (int q = t; q < 4096; q += 256) {
        const int i = q >> 6, c = q & 63;
        const float ls = deg_row[i] * S[i * 64 + c] - AS64[q];
        trl += ls * FFt[c * 64 + i];
    }
    if (t < 64) { trg = GP[t * 65]; u2 = u_vec[t] * u_vec[t]; sz2 = sizes[t] * sizes[t]; }
    sA = bred256(sA, red);
    trl = bred256(trl, red);
    trg = bred256(trg, red);
    u2 = bred256(u2, red);
    sz2 = bred256(sz2, red);
    if (t == 0) {
        const float m = scal[0], sumF2 = scal[1], gfp = scal[2], lad = scal[3];
        const float spectral = -(trg - u2 / (2.f * m)) / (2.f * m);
        const float collapse = sqrtf(sz2) / fn * 8.f - 1.f;
        const float frob = sqrtf(fmaxf(sA - 2.f * gfp + sumF2, 0.f)) * 1e-4f;
        const float one_two = sqrtf(sz2) * 1e-4f;
        const float smooth = lad * (-1e-4f);
        out_loss[0] = spectral + 0.1f * collapse + smooth + trl + frob + one_two;
    }
}

extern "C" void kernel_launch(void* const* d_in, const int* in_sizes, int n_in,
                              void* d_out, int out_size, void* d_ws, size_t ws_size,
                              hipStream_t stream) {
    const float* F = (const float*)d_in[0];
    const int* esrc = (const int*)d_in[1];     // int inputs arrive as int32
    const int* edst = (const int*)d_in[2];
    const float* ev = (const float*)d_in[3];
    const float* Wg = (const float*)d_in[4];
    const float* bg = (const float*)d_in[5];
    const int n = in_sizes[0] / 512;
    const int E = in_sizes[1];

    float* outF = (float*)d_out;                 // FP [64*512]
    float* outS = outF + 64 * 512;               // S [n*64]
    float* outL = outS + (size_t)n * 64;         // loss scalar

    char* w = (char*)d_ws;
    float* deg_row = (float*)w;                  // n
    float* deg_col = deg_row + n;                // n
    int* cnt = (int*)(deg_col + n);              // n
    float* sizes = (float*)(cnt + n);            // 64
    float* u_vec = sizes + 64;                   // 64
    float* scal = u_vec + 64;                    // 64 (m, sumF2, gfp, logabsdet)
    float* G = scal + 64;                        // 64*512
    float* GP = G + 64 * 512;                    // 4096
    float* SS = GP + 4096;                       // 4096
    float* SDS = SS + 4096;                      // 4096
    float* AS64 = SDS + 4096;                    // 4096
    float* FFt = AS64 + 4096;                    // 4096
    float* zend = FFt + 4096;
    const size_t zero_bytes = (size_t)((char*)zend - w);
    int* row_start = (int*)zend;                 // n+8
    int* cursor = row_start + (n + 8);           // n
    u16* Sbf = (u16*)(cursor + n);               // n*64
    u16* ASbf = Sbf + (size_t)n * 64;            // n*64
    u16* Wt = ASbf + (size_t)n * 64;             // 64*512
    int2* sedge = (int2*)(Wt + 64 * 512);        // E

    hipMemsetAsync(d_ws, 0, zero_bytes, stream);
    k_prep<<<128, 256, 0, stream>>>(Wg, Wt);
    k_deg<<<2048, 256, 0, stream>>>(esrc, edst, ev, E, deg_row, deg_col, cnt, scal);
    k1<<<n / 64, 256, 0, stream>>>(F, Wt, bg, outS, Sbf, sizes, scal);
    k_scan<<<1, 1024, 0, stream>>>(cnt, row_start, cursor, n);
    k_scatter<<<2048, 256, 0, stream>>>(esrc, edst, ev, E, cursor, sedge);
    k2<<<(n / 1024) * 8, 256, 0, stream>>>(F, outS, G);
    k_as<<<n / 4, 256, 0, stream>>>(row_start, sedge, Sbf, ASbf);
    k_as64<<<64, 64, 0, stream>>>(row_start, sedge, outS, AS64);
    k_kk<<<(n / 512) * 4, 256, 0, stream>>>(Sbf, ASbf, deg_row, deg_col, GP, SS, SDS, u_vec);
    k_fp<<<128, 256, 0, stream>>>(G, sizes, outF, scal);
    k_fft<<<64, 256, 0, stream>>>(outF, FFt);
    k_lu<<<1, 64, 0, stream>>>(SDS, GP, scal);
    k_final<<<1, 256, 0, stream>>>(GP, SS, FFt, u_vec, sizes, deg_row, AS64, outS, scal, outL, (float)n);
}

// Round 3
// 1163.744 us; speedup vs baseline: 1.2746x; 1.2746x over previous
//
#include <hip/hip_runtime.h>
#include <hip/hip_bf16.h>
#include <cstdint>
#include <cstddef>

typedef unsigned short u16;
typedef float f32x4 __attribute__((ext_vector_type(4)));
typedef short bf16x8 __attribute__((ext_vector_type(8)));
typedef unsigned short u16x8 __attribute__((ext_vector_type(8)));

__device__ __forceinline__ u16 f2bf(float f) {
    uint32_t u = __float_as_uint(f);
    u += 0x7fffu + ((u >> 16) & 1u);
    return (u16)(u >> 16);
}
__device__ __forceinline__ float bf2f(u16 h) {
    return __uint_as_float(((uint32_t)h) << 16);
}

// ---------------- W pre-transpose + swizzle: Wt[c*512 + (k ^ ((c&7)<<3))] = bf16(W[k*64+c])
__global__ __launch_bounds__(256) void k_prep(const float* __restrict__ Wg, u16* __restrict__ Wt) {
    int idx = blockIdx.x * 256 + threadIdx.x;   // 32768
    int k = idx >> 6, c = idx & 63;
    int lin = c * 512 + (k ^ ((c & 7) << 3));
    Wt[lin] = f2bf(Wg[idx]);
}

// ---------------- degrees + histogram + m   (edges are int32 per harness ABI!)
__global__ __launch_bounds__(256) void k_deg(const int* __restrict__ esrc,
    const int* __restrict__ edst, const float* __restrict__ ev, const int E,
    float* __restrict__ deg_row, float* __restrict__ deg_col, int* __restrict__ cnt,
    float* __restrict__ scal) {
    const int gid = blockIdx.x * 256 + threadIdx.x;
    const int stride = gridDim.x * 256;
    float vsum = 0.f;
    for (int e = gid; e < E; e += stride) {
        const int s = esrc[e], t = edst[e];
        const float v = ev[e];
        atomicAdd(deg_row + s, v);
        atomicAdd(deg_col + t, v);
        atomicAdd(cnt + s, 1);
        vsum += v;
    }
    #pragma unroll
    for (int mm = 1; mm < 64; mm <<= 1) vsum += __shfl_xor(vsum, mm);
    if ((threadIdx.x & 63) == 0) atomicAdd(scal + 0, vsum);
}

// ---------------- fused logits GEMM + softmax  (BM=64, 4 waves x 16 rows, full N=64)
__global__ __launch_bounds__(256) void k1(const float* __restrict__ F,
    const u16* __restrict__ WtG, const float* __restrict__ bias,
    float* __restrict__ S_out, u16* __restrict__ Sbf,
    float* __restrict__ sizes, float* __restrict__ scal) {
    __shared__ __align__(16) u16 Wl[64 * 512];
    __shared__ __align__(16) u16 Al[64 * 64];
    __shared__ float red4[4];
    const int tid = threadIdx.x;
    const int row0 = blockIdx.x * 64;
    for (int j = tid; j < 4096; j += 256)
        ((uint4*)Wl)[j] = ((const uint4*)WtG)[j];

    const int lane = tid & 63;
    const int wv = __builtin_amdgcn_readfirstlane(tid >> 6);
    const int l15 = lane & 15, lq = lane >> 4;
    f32x4 acc[4];
    #pragma unroll
    for (int tn = 0; tn < 4; tn++)
        #pragma unroll
        for (int e = 0; e < 4; e++) acc[tn][e] = 0.f;
    float sumf2 = 0.f;
    const int sr = tid >> 2, skq = tid & 3;
    const int sw = (sr & 7) << 3;

    for (int k0 = 0; k0 < 512; k0 += 64) {
        const float* fp = F + (size_t)(row0 + sr) * 512 + k0 + skq * 16;
        float4 v[4];
        u16 h[16];
        #pragma unroll
        for (int q = 0; q < 4; q++) v[q] = ((const float4*)fp)[q];
        #pragma unroll
        for (int q = 0; q < 4; q++) {
            sumf2 += v[q].x * v[q].x + v[q].y * v[q].y + v[q].z * v[q].z + v[q].w * v[q].w;
            h[q * 4 + 0] = f2bf(v[q].x); h[q * 4 + 1] = f2bf(v[q].y);
            h[q * 4 + 2] = f2bf(v[q].z); h[q * 4 + 3] = f2bf(v[q].w);
        }
        #pragma unroll
        for (int half = 0; half < 2; half++) {
            u16x8 pk;
            #pragma unroll
            for (int e2 = 0; e2 < 8; e2++) pk[e2] = h[half * 8 + e2];
            *(u16x8*)&Al[sr * 64 + ((skq * 16 + half * 8) ^ sw)] = pk;
        }
        __syncthreads();
        #pragma unroll
        for (int kk = 0; kk < 64; kk += 32) {
            const int arow = wv * 16 + l15;
            bf16x8 a = *(const bf16x8*)&Al[arow * 64 + ((kk + lq * 8) ^ ((arow & 7) << 3))];
            #pragma unroll
            for (int tn = 0; tn < 4; tn++) {
                const int bc = tn * 16 + l15;
                bf16x8 b = *(const bf16x8*)&Wl[bc * 512 + ((k0 + kk + lq * 8) ^ ((bc & 7) << 3))];
                acc[tn] = __builtin_amdgcn_mfma_f32_16x16x32_bf16(a, b, acc[tn], 0, 0, 0);
            }
        }
        __syncthreads();
    }

    // softmax epilogue: lane holds rows (lq*4+r), cols (l15 + 16*tn)
    float bias4[4], szacc[4] = {0.f, 0.f, 0.f, 0.f};
    #pragma unroll
    for (int tn = 0; tn < 4; tn++) bias4[tn] = bias[tn * 16 + l15];
    #pragma unroll
    for (int r2 = 0; r2 < 4; r2++) {
        float L[4];
        #pragma unroll
        for (int tn = 0; tn < 4; tn++) L[tn] = acc[tn][r2] + bias4[tn];
        float mx = fmaxf(fmaxf(L[0], L[1]), fmaxf(L[2], L[3]));
        #pragma unroll
        for (int mm = 1; mm < 16; mm <<= 1) mx = fmaxf(mx, __shfl_xor(mx, mm));
        float e[4], s = 0.f;
        #pragma unroll
        for (int tn = 0; tn < 4; tn++) { e[tn] = __expf(L[tn] - mx); s += e[tn]; }
        #pragma unroll
        for (int mm = 1; mm < 16; mm <<= 1) s += __shfl_xor(s, mm);
        const float inv = 1.f / s;
        const size_t grow = (size_t)(row0 + wv * 16 + lq * 4 + r2);
        #pragma unroll
        for (int tn = 0; tn < 4; tn++) {
            const float svl = e[tn] * inv;
            S_out[grow * 64 + tn * 16 + l15] = svl;
            Sbf[grow * 64 + tn * 16 + l15] = f2bf(svl);
            szacc[tn] += svl;
        }
    }
    #pragma unroll
    for (int tn = 0; tn < 4; tn++) {
        float vs = szacc[tn];
        vs += __shfl_xor(vs, 16);
        vs += __shfl_xor(vs, 32);
        if (lq == 0) atomicAdd(sizes + tn * 16 + l15, vs);
    }
    #pragma unroll
    for (int mm = 1; mm < 64; mm <<= 1) sumf2 += __shfl_xor(sumf2, mm);
    if (lane == 0) red4[wv] = sumf2;
    __syncthreads();
    if (tid == 0) atomicAdd(scal + 1, red4[0] + red4[1] + red4[2] + red4[3]);
}

// ---------------- exclusive scan of cnt -> row_start, cursor (single block)
__global__ __launch_bounds__(1024) void k_scan(const int* __restrict__ cnt,
    int* __restrict__ row_start, int* __restrict__ cursor, const int n) {
    __shared__ int lds[1024];
    const int t = threadIdx.x;
    const int per = n >> 10;
    const int base = t * per;
    int s = 0;
    for (int j = 0; j < per; j++) s += cnt[base + j];
    lds[t] = s;
    __syncthreads();
    for (int off = 1; off < 1024; off <<= 1) {
        int v = (t >= off) ? lds[t - off] : 0;
        __syncthreads();
        lds[t] += v;
        __syncthreads();
    }
    int run = lds[t] - s;
    for (int j = 0; j < per; j++) {
        const int idx = base + j;
        row_start[idx] = run;
        cursor[idx] = run;
        run += cnt[idx];
    }
    if (t == 1023) row_start[n] = run;
}

// ---------------- counting-sort scatter  (edges int32)
__global__ __launch_bounds__(256) void k_scatter(const int* __restrict__ esrc,
    const int* __restrict__ edst, const float* __restrict__ ev, const int E,
    int* __restrict__ cursor, int2* __restrict__ sedge) {
    const int gid = blockIdx.x * 256 + threadIdx.x;
    const int stride = gridDim.x * 256;
    for (int e = gid; e < E; e += stride) {
        const int s = esrc[e];
        const int pos = atomicAdd(cursor + s, 1);
        sedge[pos] = make_int2(edst[e], __float_as_int(ev[e]));
    }
}

// ---------------- k2m: G = S^T F via MFMA.
// Grid: 512 blocks = (kblk 128) x (d-slice 4 of 128 cols). Each block: 512 rows,
// processed in 8 chunks of KK=64 rows. LDS layouts (u32 words, word = bf16 pair
// of consecutive rows i=2w,2w+1):
//   Ss[c][w]: word = c*32 + (w ^ (((c>>2)&7)<<2))   c=0..63
//   Fs[d][w]: word = d*32 + (w ^ (((d>>2)&7)<<2))   d=0..127 (relative)
// MFMA fragments read as ds_read_b128 (4 consecutive swizzled words = 8 rows i).
__global__ __launch_bounds__(256) void k2m(const float* __restrict__ F,
    const u16* __restrict__ Sbf, float* __restrict__ G) {
    __shared__ uint32_t Ss[64 * 32];
    __shared__ uint32_t Fs[128 * 32];
    const int tid = threadIdx.x;
    const int lane = tid & 63;
    const int wv = __builtin_amdgcn_readfirstlane(tid >> 6);
    const int l15 = lane & 15, lq = lane >> 4;
    const int d0 = (blockIdx.x & 3) * 128;
    const int kblk = blockIdx.x >> 2;

    f32x4 acc[8];
    #pragma unroll
    for (int t8 = 0; t8 < 8; t8++)
        #pragma unroll
        for (int r = 0; r < 4; r++) acc[t8][r] = 0.f;

    // staging index precompute
    const int s_ip = tid >> 3;            // 0..31 (S i-pair)
    const int s_cs = (tid & 7) * 8;       // 0..56 (S col base)
    const int f_dg = tid & 31;            // d group (4 cols)
    const int f_ipb = tid >> 5;           // 0..7, +8s -> i-pair

    for (int ch = 0; ch < 8; ch++) {
        const int i0 = kblk * 512 + ch * 64;
        // ---- stage S chunk: rows i0..i0+63, cols 0..63
        {
            const u16x8 r0 = *(const u16x8*)&Sbf[(size_t)(i0 + 2 * s_ip) * 64 + s_cs];
            const u16x8 r1 = *(const u16x8*)&Sbf[(size_t)(i0 + 2 * s_ip + 1) * 64 + s_cs];
            #pragma unroll
            for (int j = 0; j < 8; j++) {
                const int c = s_cs + j;
                const uint32_t pk = (uint32_t)(u16)r0[j] | ((uint32_t)(u16)r1[j] << 16);
                Ss[c * 32 + (s_ip ^ (((c >> 2) & 7) << 2))] = pk;
            }
        }
        // ---- stage F chunk: rows i0..i0+63, cols d0..d0+127 (bf16 convert)
        #pragma unroll
        for (int s = 0; s < 4; s++) {
            const int ip = f_ipb + 8 * s;
            const float4 a = *(const float4*)(F + (size_t)(i0 + 2 * ip) * 512 + d0 + 4 * f_dg);
            const float4 b = *(const float4*)(F + (size_t)(i0 + 2 * ip + 1) * 512 + d0 + 4 * f_dg);
            const float al[4] = {a.x, a.y, a.z, a.w};
            const float bl[4] = {b.x, b.y, b.z, b.w};
            #pragma unroll
            for (int j = 0; j < 4; j++) {
                const int d = 4 * f_dg + j;
                const uint32_t pk = (uint32_t)f2bf(al[j]) | ((uint32_t)f2bf(bl[j]) << 16);
                Fs[d * 32 + (ip ^ (((d >> 2) & 7) << 2))] = pk;
            }
        }
        __syncthreads();
        // ---- MFMA: wave wv owns c-tile [16wv,16wv+16), all 8 d-tiles
        #pragma unroll
        for (int kk = 0; kk < 64; kk += 32) {
            const int w0 = (kk >> 1) + (lq << 2);
            const int ca = 16 * wv + l15;
            const bf16x8 afrag = *(const bf16x8*)&Ss[ca * 32 + (w0 ^ (((ca >> 2) & 7) << 2))];
            #pragma unroll
            for (int t8 = 0; t8 < 8; t8++) {
                const int d = 16 * t8 + l15;
                const bf16x8 bfrag = *(const bf16x8*)&Fs[d * 32 + (w0 ^ (((d >> 2) & 7) << 2))];
                acc[t8] = __builtin_amdgcn_mfma_f32_16x16x32_bf16(afrag, bfrag, acc[t8], 0, 0, 0);
            }
        }
        __syncthreads();
    }
    // ---- epilogue: atomic partials into G[c][d]
    #pragma unroll
    for (int t8 = 0; t8 < 8; t8++) {
        #pragma unroll
        for (int r = 0; r < 4; r++) {
            const int c = 16 * wv + 4 * lq + r;
            const int d = d0 + 16 * t8 + l15;
            atomicAdd(G + (size_t)c * 512 + d, acc[t8][r]);
        }
    }
}

// ---------------- AS rows (bf16), wave per row, lane = cluster
__global__ __launch_bounds__(256) void k_as(const int* __restrict__ row_start,
    const int2* __restrict__ sedge, const u16* __restrict__ Sbf, u16* __restrict__ ASbf) {
    const int lane = threadIdx.x & 63;
    const int wv = __builtin_amdgcn_readfirstlane((int)(threadIdx.x >> 6));
    const int i = blockIdx.x * 4 + wv;
    const int e0 = row_start[i], e1 = row_start[i + 1];
    float acc = 0.f;
    for (int e = e0; e < e1; e++) {
        const int2 p = sedge[e];
        acc = fmaf(__int_as_float(p.y), bf2f(Sbf[(size_t)p.x * 64 + lane]), acc);
    }
    ASbf[(size_t)i * 64 + lane] = f2bf(acc);
}

// ---------------- exact f32 AS rows 0..63 (trace_loss path)
__global__ __launch_bounds__(64) void k_as64(const int* __restrict__ row_start,
    const int2* __restrict__ sedge, const float* __restrict__ S, float* __restrict__ AS64) {
    const int lane = threadIdx.x;
    const int i = blockIdx.x;
    const int e0 = row_start[i], e1 = row_start[i + 1];
    float acc = 0.f;
    for (int e = e0; e < e1; e++) {
        const int2 p = sedge[e];
        acc = fmaf(__int_as_float(p.y), S[(size_t)p.x * 64 + lane], acc);
    }
    AS64[i * 64 + lane] = acc;
}

// ---------------- fused k x k reductions: GP=AS^T S, SS=S^T S, SDS=(deg.S)^T S, u=S^T deg_col
__global__ __launch_bounds__(256) void k_kk(const u16* __restrict__ Sbf,
    const u16* __restrict__ ASbf, const float* __restrict__ deg_row,
    const float* __restrict__ deg_col, float* __restrict__ GP, float* __restrict__ SS,
    float* __restrict__ SDS, float* __restrict__ u_vec) {
    __shared__ float Pgp[4][16][64];
    __shared__ float Pss[4][16][64];
    __shared__ float Psds[4][16][64];
    __shared__ float Pu[4][64];
    const int tid = threadIdx.x, lane = tid & 63;
    const int wv = __builtin_amdgcn_readfirstlane(tid >> 6);
    const int cs = blockIdx.x & 3, c0 = cs * 16;
    const int rbase = (blockIdx.x >> 2) * 512 + wv * 128;
    float gp[16], ss[16], sds[16], ua = 0.f;
    #pragma unroll
    for (int cc = 0; cc < 16; cc++) { gp[cc] = 0.f; ss[cc] = 0.f; sds[cc] = 0.f; }
    for (int r = 0; r < 128; r++) {
        const int i = rbase + r;
        const float sv = bf2f(Sbf[(size_t)i * 64 + lane]);
        const float dr = deg_row[i];
        ua = fmaf(deg_col[i], sv, ua);
        const u16* srow = Sbf + (size_t)i * 64 + c0;
        const u16* arow = ASbf + (size_t)i * 64 + c0;
        #pragma unroll
        for (int cc = 0; cc < 16; cc++) {
            const float sc = bf2f(srow[cc]);
            const float ac = bf2f(arow[cc]);
            ss[cc] = fmaf(sc, sv, ss[cc]);
            sds[cc] = fmaf(sc * dr, sv, sds[cc]);
            gp[cc] = fmaf(ac, sv, gp[cc]);
        }
    }
    #pragma unroll
    for (int cc = 0; cc < 16; cc++) {
        Pgp[wv][cc][lane] = gp[cc]; Pss[wv][cc][lane] = ss[cc]; Psds[wv][cc][lane] = sds[cc];
    }
    Pu[wv][lane] = ua;
    __syncthreads();
    for (int q = 0; q < 4; q++) {
        const int cell = tid * 4 + q, cc = cell >> 6, l = cell & 63;
        atomicAdd(GP + (c0 + cc) * 64 + l, Pgp[0][cc][l] + Pgp[1][cc][l] + Pgp[2][cc][l] + Pgp[3][cc][l]);
        atomicAdd(SS + (c0 + cc) * 64 + l, Pss[0][cc][l] + Pss[1][cc][l] + Pss[2][cc][l] + Pss[3][cc][l]);
        atomicAdd(SDS + (c0 + cc) * 64 + l, Psds[0][cc][l] + Psds[1][cc][l] + Psds[2][cc][l] + Psds[3][cc][l]);
    }
    if (cs == 0 && tid < 64)
        atomicAdd(u_vec + tid, Pu[0][tid] + Pu[1][tid] + Pu[2][tid] + Pu[3][tid]);
}

__device__ __forceinline__ float bred256(float v, float* red) {
    #pragma unroll
    for (int mm = 1; mm < 64; mm <<= 1) v += __shfl_xor(v, mm);
    const int t = threadIdx.x;
    __syncthreads();
    if ((t & 63) == 0) red[t >> 6] = v;
    __syncthreads();
    return red[0] + red[1] + red[2] + red[3];
}

// ---------------- FP = selu(G/sizes) + <G,FP>
__global__ __launch_bounds__(256) void k_fp(const float* __restrict__ G,
    const float* __restrict__ sizes, float* __restrict__ FP, float* __restrict__ scal) {
    __shared__ float red[4];
    const int idx = blockIdx.x * 256 + threadIdx.x;
    const int c = idx >> 9;
    const float g = G[idx];
    const float x = g / sizes[c];
    const float fp = 1.0507009873554805f * (x > 0.f ? x : 1.6732632423543772f * (__expf(x) - 1.f));
    FP[idx] = fp;
    const float gd = bred256(g * fp, red);
    if (threadIdx.x == 0) atomicAdd(scal + 2, gd);
}

// ---------------- FFt = FP FP^T
__global__ __launch_bounds__(256) void k_fft(const float* __restrict__ FP, float* __restrict__ FFt) {
    __shared__ float red[256];
    const int c = blockIdx.x;
    const int cp = threadIdx.x & 63, part = threadIdx.x >> 6;
    float a = 0.f;
    const int dbase = part * 128;
    for (int dd = 0; dd < 128; dd++)
        a = fmaf(FP[c * 512 + dbase + dd], FP[cp * 512 + dbase + dd], a);
    red[threadIdx.x] = a;
    __syncthreads();
    if (threadIdx.x < 64)
        FFt[c * 64 + threadIdx.x] = red[threadIdx.x] + red[threadIdx.x + 64] +
                                    red[threadIdx.x + 128] + red[threadIdx.x + 192];
}

// ---------------- logabsdet(StLS + 1) via LU w/ partial pivoting (1 wave)
__global__ __launch_bounds__(64) void k_lu(const float* __restrict__ SDS,
    const float* __restrict__ GP, float* __restrict__ scal) {
    __shared__ float M[64][65];
    const int l = threadIdx.x;
    for (int c = 0; c < 64; c++) M[l][c] = SDS[l * 64 + c] - GP[l * 64 + c] + 1.0f;
    __syncthreads();
    float logdet = 0.f;
    for (int k = 0; k < 64; k++) {
        float v = (l >= k) ? fabsf(M[l][k]) : -1.f;
        int idx = l;
        #pragma unroll
        for (int mm = 1; mm < 64; mm <<= 1) {
            const float ov = __shfl_xor(v, mm);
            const int oi = __shfl_xor(idx, mm);
            if (ov > v || (ov == v && oi < idx)) { v = ov; idx = oi; }
        }
        if (idx != k) {
            const float t1 = M[k][l], t2 = M[idx][l];
            __syncthreads();
            M[k][l] = t2;
            M[idx][l] = t1;
        }
        __syncthreads();
        const float piv = M[k][k];
        logdet += logf(fabsf(piv));
        if (l > k) {
            const float f = M[l][k] / piv;
            for (int c = k + 1; c < 64; c++) M[l][c] = fmaf(-f, M[k][c], M[l][c]);
        }
        __syncthreads();
    }
    if (l == 0) scal[3] = logdet;
}

// ---------------- final loss assembly
__global__ __launch_bounds__(256) void k_final(const float* __restrict__ GP,
    const float* __restrict__ SS, const float* __restrict__ FFt, const float* __restrict__ u_vec,
    const float* __restrict__ sizes, const float* __restrict__ deg_row,
    const float* __restrict__ AS64, const float* __restrict__ S,
    const float* __restrict__ scal, float* __restrict__ out_loss, const float fn) {
    __shared__ float red[4];
    const int t = threadIdx.x;
    float sA = 0.f, trl = 0.f, trg = 0.f, u2 = 0.f, sz2 = 0.f;
    for (int q = t; q < 4096; q += 256) sA += SS[q] * FFt[q];
    for (int q = t; q < 4096; q += 256) {
        const int i = q >> 6, c = q & 63;
        const float ls = deg_row[i] * S[i * 64 + c] - AS64[q];
        trl += ls * FFt[c * 64 + i];
    }
    if (t < 64) { trg = GP[t * 65]; u2 = u_vec[t] * u_vec[t]; sz2 = sizes[t] * sizes[t]; }
    sA = bred256(sA, red);
    trl = bred256(trl, red);
    trg = bred256(trg, red);
    u2 = bred256(u2, red);
    sz2 = bred256(sz2, red);
    if (t == 0) {
        const float m = scal[0], sumF2 = scal[1], gfp = scal[2], lad = scal[3];
        const float spectral = -(trg - u2 / (2.f * m)) / (2.f * m);
        const float collapse = sqrtf(sz2) / fn * 8.f - 1.f;
        const float frob = sqrtf(fmaxf(sA - 2.f * gfp + sumF2, 0.f)) * 1e-4f;
        const float one_two = sqrtf(sz2) * 1e-4f;
        const float smooth = lad * (-1e-4f);
        out_loss[0] = spectral + 0.1f * collapse + smooth + trl + frob + one_two;
    }
}

extern "C" void kernel_launch(void* const* d_in, const int* in_sizes, int n_in,
                              void* d_out, int out_size, void* d_ws, size_t ws_size,
                              hipStream_t stream) {
    const float* F = (const float*)d_in[0];
    const int* esrc = (const int*)d_in[1];     // int inputs arrive as int32
    const int* edst = (const int*)d_in[2];
    const float* ev = (const float*)d_in[3];
    const float* Wg = (const float*)d_in[4];
    const float* bg = (const float*)d_in[5];
    const int n = in_sizes[0] / 512;
    const int E = in_sizes[1];

    float* outF = (float*)d_out;                 // FP [64*512]
    float* outS = outF + 64 * 512;               // S [n*64]
    float* outL = outS + (size_t)n * 64;         // loss scalar

    char* w = (char*)d_ws;
    float* deg_row = (float*)w;                  // n
    float* deg_col = deg_row + n;                // n
    int* cnt = (int*)(deg_col + n);              // n
    float* sizes = (float*)(cnt + n);            // 64
    float* u_vec = sizes + 64;                   // 64
    float* scal = u_vec + 64;                    // 64 (m, sumF2, gfp, logabsdet)
    float* G = scal + 64;                        // 64*512
    float* GP = G + 64 * 512;                    // 4096
    float* SS = GP + 4096;                       // 4096
    float* SDS = SS + 4096;                      // 4096
    float* AS64 = SDS + 4096;                    // 4096
    float* FFt = AS64 + 4096;                    // 4096
    float* zend = FFt + 4096;
    const size_t zero_bytes = (size_t)((char*)zend - w);
    int* row_start = (int*)zend;                 // n+8
    int* cursor = row_start + (n + 8);           // n
    u16* Sbf = (u16*)(cursor + n);               // n*64
    u16* ASbf = Sbf + (size_t)n * 64;            // n*64
    u16* Wt = ASbf + (size_t)n * 64;             // 64*512
    int2* sedge = (int2*)(Wt + 64 * 512);        // E

    hipMemsetAsync(d_ws, 0, zero_bytes, stream);
    k_prep<<<128, 256, 0, stream>>>(Wg, Wt);
    k_deg<<<2048, 256, 0, stream>>>(esrc, edst, ev, E, deg_row, deg_col, cnt, scal);
    k1<<<n / 64, 256, 0, stream>>>(F, Wt, bg, outS, Sbf, sizes, scal);
    k_scan<<<1, 1024, 0, stream>>>(cnt, row_start, cursor, n);
    k_scatter<<<2048, 256, 0, stream>>>(esrc, edst, ev, E, cursor, sedge);
    k2m<<<512, 256, 0, stream>>>(F, Sbf, G);
    k_as<<<n / 4, 256, 0, stream>>>(row_start, sedge, Sbf, ASbf);
    k_as64<<<64, 64, 0, stream>>>(row_start, sedge, outS, AS64);
    k_kk<<<(n / 512) * 4, 256, 0, stream>>>(Sbf, ASbf, deg_row, deg_col, GP, SS, SDS, u_vec);
    k_fp<<<128, 256, 0, stream>>>(G, sizes, outF, scal);
    k_fft<<<64, 256, 0, stream>>>(outF, FFt);
    k_lu<<<1, 64, 0, stream>>>(SDS, GP, scal);
    k_final<<<1, 256, 0, stream>>>(GP, SS, FFt, u_vec, sizes, deg_row, AS64, outS, scal, outL, (float)n);
}

// Round 4
// 857.794 us; speedup vs baseline: 1.7292x; 1.3567x over previous
//
#include <hip/hip_runtime.h>
#include <hip/hip_bf16.h>
#include <cstdint>
#include <cstddef>

typedef unsigned short u16;
typedef float f32x4 __attribute__((ext_vector_type(4)));
typedef short bf16x8 __attribute__((ext_vector_type(8)));
typedef unsigned short u16x8 __attribute__((ext_vector_type(8)));

__device__ __forceinline__ u16 f2bf(float f) {
    uint32_t u = __float_as_uint(f);
    u += 0x7fffu + ((u >> 16) & 1u);
    return (u16)(u >> 16);
}
__device__ __forceinline__ float bf2f(u16 h) {
    return __uint_as_float(((uint32_t)h) << 16);
}

// ---------------- W pre-transpose + swizzle
__global__ __launch_bounds__(256) void k_prep(const float* __restrict__ Wg, u16* __restrict__ Wt) {
    int idx = blockIdx.x * 256 + threadIdx.x;   // 32768
    int k = idx >> 6, c = idx & 63;
    int lin = c * 512 + (k ^ ((c & 7) << 3));
    Wt[lin] = f2bf(Wg[idx]);
}

// ---------------- histogram (XCD-private copies) + m
__global__ __launch_bounds__(256) void k_deg(const int* __restrict__ esrc,
    const float* __restrict__ ev, const int E, int* __restrict__ cnt8, const int n,
    float* __restrict__ scal) {
    const int gid = blockIdx.x * 256 + threadIdx.x;
    const int stride = gridDim.x * 256;
    int* __restrict__ my = cnt8 + (size_t)(blockIdx.x & 7) * n;
    float vsum = 0.f;
    for (int e = gid; e < E; e += stride) {
        atomicAdd(my + esrc[e], 1);
        vsum += ev[e];
    }
    #pragma unroll
    for (int mm = 1; mm < 64; mm <<= 1) vsum += __shfl_xor(vsum, mm);
    if ((threadIdx.x & 63) == 0) atomicAdd(scal + 0, vsum);
}

// ---------------- merge 8 copies -> cnt + per-block sums
__global__ __launch_bounds__(256) void k_merge(const int* __restrict__ cnt8, const int n,
    int* __restrict__ cnt, int* __restrict__ blocksum) {
    __shared__ int red[4];
    const int i = blockIdx.x * 256 + threadIdx.x;
    int s = 0;
    #pragma unroll
    for (int c = 0; c < 8; c++) s += cnt8[(size_t)c * n + i];
    cnt[i] = s;
    int r = s;
    #pragma unroll
    for (int mm = 1; mm < 64; mm <<= 1) r += __shfl_xor(r, mm);
    if ((threadIdx.x & 63) == 0) red[threadIdx.x >> 6] = r;
    __syncthreads();
    if (threadIdx.x == 0) blocksum[blockIdx.x] = red[0] + red[1] + red[2] + red[3];
}

// ---------------- scan 256 block sums
__global__ __launch_bounds__(256) void k_scan2(const int* __restrict__ blocksum,
    int* __restrict__ blockoff, int* __restrict__ row_start, const int n, const int E) {
    __shared__ int lds[256];
    const int t = threadIdx.x;
    const int v = blocksum[t];
    lds[t] = v;
    __syncthreads();
    for (int off = 1; off < 256; off <<= 1) {
        int x = (t >= off) ? lds[t - off] : 0;
        __syncthreads();
        lds[t] += x;
        __syncthreads();
    }
    blockoff[t] = lds[t] - v;
    if (t == 0) row_start[n] = E;
}

// ---------------- per-element scan -> row_start + cursor8
__global__ __launch_bounds__(256) void k_scan3(const int* __restrict__ cnt,
    const int* __restrict__ cnt8, const int* __restrict__ blockoff,
    int* __restrict__ row_start, int* __restrict__ cursor8, const int n) {
    __shared__ int lds[256];
    const int t = threadIdx.x;
    const int i = blockIdx.x * 256 + t;
    const int v = cnt[i];
    lds[t] = v;
    __syncthreads();
    for (int off = 1; off < 256; off <<= 1) {
        int x = (t >= off) ? lds[t - off] : 0;
        __syncthreads();
        lds[t] += x;
        __syncthreads();
    }
    int run = blockoff[blockIdx.x] + lds[t] - v;
    row_start[i] = run;
    #pragma unroll
    for (int c = 0; c < 8; c++) {
        cursor8[(size_t)c * n + i] = run;
        run += cnt8[(size_t)c * n + i];
    }
}

// ---------------- fused logits GEMM + softmax
__global__ __launch_bounds__(256) void k1(const float* __restrict__ F,
    const u16* __restrict__ WtG, const float* __restrict__ bias,
    float* __restrict__ S_out, u16* __restrict__ Sbf,
    float* __restrict__ sizes, float* __restrict__ scal) {
    __shared__ __align__(16) u16 Wl[64 * 512];
    __shared__ __align__(16) u16 Al[64 * 64];
    __shared__ float red4[4];
    const int tid = threadIdx.x;
    const int row0 = blockIdx.x * 64;
    for (int j = tid; j < 4096; j += 256)
        ((uint4*)Wl)[j] = ((const uint4*)WtG)[j];

    const int lane = tid & 63;
    const int wv = __builtin_amdgcn_readfirstlane(tid >> 6);
    const int l15 = lane & 15, lq = lane >> 4;
    f32x4 acc[4];
    #pragma unroll
    for (int tn = 0; tn < 4; tn++)
        #pragma unroll
        for (int e = 0; e < 4; e++) acc[tn][e] = 0.f;
    float sumf2 = 0.f;
    const int sr = tid >> 2, skq = tid & 3;
    const int sw = (sr & 7) << 3;

    for (int k0 = 0; k0 < 512; k0 += 64) {
        const float* fp = F + (size_t)(row0 + sr) * 512 + k0 + skq * 16;
        float4 v[4];
        u16 h[16];
        #pragma unroll
        for (int q = 0; q < 4; q++) v[q] = ((const float4*)fp)[q];
        #pragma unroll
        for (int q = 0; q < 4; q++) {
            sumf2 += v[q].x * v[q].x + v[q].y * v[q].y + v[q].z * v[q].z + v[q].w * v[q].w;
            h[q * 4 + 0] = f2bf(v[q].x); h[q * 4 + 1] = f2bf(v[q].y);
            h[q * 4 + 2] = f2bf(v[q].z); h[q * 4 + 3] = f2bf(v[q].w);
        }
        #pragma unroll
        for (int half = 0; half < 2; half++) {
            u16x8 pk;
            #pragma unroll
            for (int e2 = 0; e2 < 8; e2++) pk[e2] = h[half * 8 + e2];
            *(u16x8*)&Al[sr * 64 + ((skq * 16 + half * 8) ^ sw)] = pk;
        }
        __syncthreads();
        #pragma unroll
        for (int kk = 0; kk < 64; kk += 32) {
            const int arow = wv * 16 + l15;
            bf16x8 a = *(const bf16x8*)&Al[arow * 64 + ((kk + lq * 8) ^ ((arow & 7) << 3))];
            #pragma unroll
            for (int tn = 0; tn < 4; tn++) {
                const int bc = tn * 16 + l15;
                bf16x8 b = *(const bf16x8*)&Wl[bc * 512 + ((k0 + kk + lq * 8) ^ ((bc & 7) << 3))];
                acc[tn] = __builtin_amdgcn_mfma_f32_16x16x32_bf16(a, b, acc[tn], 0, 0, 0);
            }
        }
        __syncthreads();
    }

    float bias4[4], szacc[4] = {0.f, 0.f, 0.f, 0.f};
    #pragma unroll
    for (int tn = 0; tn < 4; tn++) bias4[tn] = bias[tn * 16 + l15];
    #pragma unroll
    for (int r2 = 0; r2 < 4; r2++) {
        float L[4];
        #pragma unroll
        for (int tn = 0; tn < 4; tn++) L[tn] = acc[tn][r2] + bias4[tn];
        float mx = fmaxf(fmaxf(L[0], L[1]), fmaxf(L[2], L[3]));
        #pragma unroll
        for (int mm = 1; mm < 16; mm <<= 1) mx = fmaxf(mx, __shfl_xor(mx, mm));
        float e[4], s = 0.f;
        #pragma unroll
        for (int tn = 0; tn < 4; tn++) { e[tn] = __expf(L[tn] - mx); s += e[tn]; }
        #pragma unroll
        for (int mm = 1; mm < 16; mm <<= 1) s += __shfl_xor(s, mm);
        const float inv = 1.f / s;
        const size_t grow = (size_t)(row0 + wv * 16 + lq * 4 + r2);
        #pragma unroll
        for (int tn = 0; tn < 4; tn++) {
            const float svl = e[tn] * inv;
            S_out[grow * 64 + tn * 16 + l15] = svl;
            Sbf[grow * 64 + tn * 16 + l15] = f2bf(svl);
            szacc[tn] += svl;
        }
    }
    #pragma unroll
    for (int tn = 0; tn < 4; tn++) {
        float vs = szacc[tn];
        vs += __shfl_xor(vs, 16);
        vs += __shfl_xor(vs, 32);
        if (lq == 0) atomicAdd(sizes + tn * 16 + l15, vs);
    }
    #pragma unroll
    for (int mm = 1; mm < 64; mm <<= 1) sumf2 += __shfl_xor(sumf2, mm);
    if (lane == 0) red4[wv] = sumf2;
    __syncthreads();
    if (tid == 0) atomicAdd(scal + 1, red4[0] + red4[1] + red4[2] + red4[3]);
}

// ---------------- counting-sort scatter (XCD-private cursors)
__global__ __launch_bounds__(256) void k_scatter(const int* __restrict__ esrc,
    const int* __restrict__ edst, const float* __restrict__ ev, const int E,
    int* __restrict__ cursor8, const int n, int2* __restrict__ sedge) {
    const int gid = blockIdx.x * 256 + threadIdx.x;
    const int stride = gridDim.x * 256;
    int* __restrict__ my = cursor8 + (size_t)(blockIdx.x & 7) * n;
    for (int e = gid; e < E; e += stride) {
        const int pos = atomicAdd(my + esrc[e], 1);
        sedge[pos] = make_int2(edst[e], __float_as_int(ev[e]));
    }
}

// ---------------- k2m: G = S^T F via MFMA
__global__ __launch_bounds__(256) void k2m(const float* __restrict__ F,
    const u16* __restrict__ Sbf, float* __restrict__ G) {
    __shared__ uint32_t Ss[64 * 32];
    __shared__ uint32_t Fs[128 * 32];
    const int tid = threadIdx.x;
    const int lane = tid & 63;
    const int wv = __builtin_amdgcn_readfirstlane(tid >> 6);
    const int l15 = lane & 15, lq = lane >> 4;
    const int d0 = (blockIdx.x & 3) * 128;
    const int kblk = blockIdx.x >> 2;

    f32x4 acc[8];
    #pragma unroll
    for (int t8 = 0; t8 < 8; t8++)
        #pragma unroll
        for (int r = 0; r < 4; r++) acc[t8][r] = 0.f;

    const int s_ip = tid >> 3;
    const int s_cs = (tid & 7) * 8;
    const int f_dg = tid & 31;
    const int f_ipb = tid >> 5;

    for (int ch = 0; ch < 8; ch++) {
        const int i0 = kblk * 512 + ch * 64;
        {
            const u16x8 r0 = *(const u16x8*)&Sbf[(size_t)(i0 + 2 * s_ip) * 64 + s_cs];
            const u16x8 r1 = *(const u16x8*)&Sbf[(size_t)(i0 + 2 * s_ip + 1) * 64 + s_cs];
            #pragma unroll
            for (int j = 0; j < 8; j++) {
                const int c = s_cs + j;
                const uint32_t pk = (uint32_t)(u16)r0[j] | ((uint32_t)(u16)r1[j] << 16);
                Ss[c * 32 + (s_ip ^ (((c >> 2) & 7) << 2))] = pk;
            }
        }
        #pragma unroll
        for (int s = 0; s < 4; s++) {
            const int ip = f_ipb + 8 * s;
            const float4 a = *(const float4*)(F + (size_t)(i0 + 2 * ip) * 512 + d0 + 4 * f_dg);
            const float4 b = *(const float4*)(F + (size_t)(i0 + 2 * ip + 1) * 512 + d0 + 4 * f_dg);
            const float al[4] = {a.x, a.y, a.z, a.w};
            const float bl[4] = {b.x, b.y, b.z, b.w};
            #pragma unroll
            for (int j = 0; j < 4; j++) {
                const int d = 4 * f_dg + j;
                const uint32_t pk = (uint32_t)f2bf(al[j]) | ((uint32_t)f2bf(bl[j]) << 16);
                Fs[d * 32 + (ip ^ (((d >> 2) & 7) << 2))] = pk;
            }
        }
        __syncthreads();
        #pragma unroll
        for (int kk = 0; kk < 64; kk += 32) {
            const int w0 = (kk >> 1) + (lq << 2);
            const int ca = 16 * wv + l15;
            const bf16x8 afrag = *(const bf16x8*)&Ss[ca * 32 + (w0 ^ (((ca >> 2) & 7) << 2))];
            #pragma unroll
            for (int t8 = 0; t8 < 8; t8++) {
                const int d = 16 * t8 + l15;
                const bf16x8 bfrag = *(const bf16x8*)&Fs[d * 32 + (w0 ^ (((d >> 2) & 7) << 2))];
                acc[t8] = __builtin_amdgcn_mfma_f32_16x16x32_bf16(afrag, bfrag, acc[t8], 0, 0, 0);
            }
        }
        __syncthreads();
    }
    #pragma unroll
    for (int t8 = 0; t8 < 8; t8++) {
        #pragma unroll
        for (int r = 0; r < 4; r++) {
            const int c = 16 * wv + 4 * lq + r;
            const int d = d0 + 16 * t8 + l15;
            atomicAdd(G + (size_t)c * 512 + d, acc[t8][r]);
        }
    }
}

// ---------------- AS rows (bf16) + deg_row, wave per row
__global__ __launch_bounds__(256) void k_as(const int* __restrict__ row_start,
    const int2* __restrict__ sedge, const u16* __restrict__ Sbf, u16* __restrict__ ASbf,
    float* __restrict__ deg_row) {
    const int lane = threadIdx.x & 63;
    const int wv = __builtin_amdgcn_readfirstlane((int)(threadIdx.x >> 6));
    const int i = blockIdx.x * 4 + wv;
    const int e0 = row_start[i], e1 = row_start[i + 1];
    float acc = 0.f, dsum = 0.f;
    for (int e = e0; e < e1; e++) {
        const int2 p = sedge[e];
        const float v = __int_as_float(p.y);
        dsum += v;
        acc = fmaf(v, bf2f(Sbf[(size_t)p.x * 64 + lane]), acc);
    }
    ASbf[(size_t)i * 64 + lane] = f2bf(acc);
    if (lane == 0) deg_row[i] = dsum;
}

// ---------------- exact f32 AS rows 0..63
__global__ __launch_bounds__(64) void k_as64(const int* __restrict__ row_start,
    const int2* __restrict__ sedge, const float* __restrict__ S, float* __restrict__ AS64) {
    const int lane = threadIdx.x;
    const int i = blockIdx.x;
    const int e0 = row_start[i], e1 = row_start[i + 1];
    float acc = 0.f;
    for (int e = e0; e < e1; e++) {
        const int2 p = sedge[e];
        acc = fmaf(__int_as_float(p.y), S[(size_t)p.x * 64 + lane], acc);
    }
    AS64[i * 64 + lane] = acc;
}

// ---------------- fused k x k reductions (deg_col == deg_row by symmetry)
__global__ __launch_bounds__(256) void k_kk(const u16* __restrict__ Sbf,
    const u16* __restrict__ ASbf, const float* __restrict__ deg_row,
    float* __restrict__ GP, float* __restrict__ SS,
    float* __restrict__ SDS, float* __restrict__ u_vec) {
    __shared__ float Pgp[4][16][64];
    __shared__ float Pss[4][16][64];
    __shared__ float Psds[4][16][64];
    __shared__ float Pu[4][64];
    const int tid = threadIdx.x, lane = tid & 63;
    const int wv = __builtin_amdgcn_readfirstlane(tid >> 6);
    const int cs = blockIdx.x & 3, c0 = cs * 16;
    const int rbase = (blockIdx.x >> 2) * 512 + wv * 128;
    float gp[16], ss[16], sds[16], ua = 0.f;
    #pragma unroll
    for (int cc = 0; cc < 16; cc++) { gp[cc] = 0.f; ss[cc] = 0.f; sds[cc] = 0.f; }
    for (int r = 0; r < 128; r++) {
        const int i = rbase + r;
        const float sv = bf2f(Sbf[(size_t)i * 64 + lane]);
        const float dr = deg_row[i];
        ua = fmaf(dr, sv, ua);
        const u16* srow = Sbf + (size_t)i * 64 + c0;
        const u16* arow = ASbf + (size_t)i * 64 + c0;
        #pragma unroll
        for (int cc = 0; cc < 16; cc++) {
            const float sc = bf2f(srow[cc]);
            const float ac = bf2f(arow[cc]);
            ss[cc] = fmaf(sc, sv, ss[cc]);
            sds[cc] = fmaf(sc * dr, sv, sds[cc]);
            gp[cc] = fmaf(ac, sv, gp[cc]);
        }
    }
    #pragma unroll
    for (int cc = 0; cc < 16; cc++) {
        Pgp[wv][cc][lane] = gp[cc]; Pss[wv][cc][lane] = ss[cc]; Psds[wv][cc][lane] = sds[cc];
    }
    Pu[wv][lane] = ua;
    __syncthreads();
    for (int q = 0; q < 4; q++) {
        const int cell = tid * 4 + q, cc = cell >> 6, l = cell & 63;
        atomicAdd(GP + (c0 + cc) * 64 + l, Pgp[0][cc][l] + Pgp[1][cc][l] + Pgp[2][cc][l] + Pgp[3][cc][l]);
        atomicAdd(SS + (c0 + cc) * 64 + l, Pss[0][cc][l] + Pss[1][cc][l] + Pss[2][cc][l] + Pss[3][cc][l]);
        atomicAdd(SDS + (c0 + cc) * 64 + l, Psds[0][cc][l] + Psds[1][cc][l] + Psds[2][cc][l] + Psds[3][cc][l]);
    }
    if (cs == 0 && tid < 64)
        atomicAdd(u_vec + tid, Pu[0][tid] + Pu[1][tid] + Pu[2][tid] + Pu[3][tid]);
}

__device__ __forceinline__ float bred256(float v, float* red) {
    #pragma unroll
    for (int mm = 1; mm < 64; mm <<= 1) v += __shfl_xor(v, mm);
    const int t = threadIdx.x;
    __syncthreads();
    if ((t & 63) == 0) red[t >> 6] = v;
    __syncthreads();
    return red[0] + red[1] + red[2] + red[3];
}

// ---------------- FP = selu(G/sizes) + <G,FP>
__global__ __launch_bounds__(256) void k_fp(const float* __restrict__ G,
    const float* __restrict__ sizes, float* __restrict__ FP, float* __restrict__ scal) {
    __shared__ float red[4];
    const int idx = blockIdx.x * 256 + threadIdx.x;
    const int c = idx >> 9;
    const float g = G[idx];
    const float x = g / sizes[c];
    const float fp = 1.0507009873554805f * (x > 0.f ? x : 1.6732632423543772f * (__expf(x) - 1.f));
    FP[idx] = fp;
    const float gd = bred256(g * fp, red);
    if (threadIdx.x == 0) atomicAdd(scal + 2, gd);
}

// ---------------- FFt = FP FP^T
__global__ __launch_bounds__(256) void k_fft(const float* __restrict__ FP, float* __restrict__ FFt) {
    __shared__ float red[256];
    const int c = blockIdx.x;
    const int cp = threadIdx.x & 63, part = threadIdx.x >> 6;
    float a = 0.f;
    const int dbase = part * 128;
    for (int dd = 0; dd < 128; dd++)
        a = fmaf(FP[c * 512 + dbase + dd], FP[cp * 512 + dbase + dd], a);
    red[threadIdx.x] = a;
    __syncthreads();
    if (threadIdx.x < 64)
        FFt[c * 64 + threadIdx.x] = red[threadIdx.x] + red[threadIdx.x + 64] +
                                    red[threadIdx.x + 128] + red[threadIdx.x + 192];
}

// ---------------- logabsdet(StLS + 1) via LU
__global__ __launch_bounds__(64) void k_lu(const float* __restrict__ SDS,
    const float* __restrict__ GP, float* __restrict__ scal) {
    __shared__ float M[64][65];
    const int l = threadIdx.x;
    for (int c = 0; c < 64; c++) M[l][c] = SDS[l * 64 + c] - GP[l * 64 + c] + 1.0f;
    __syncthreads();
    float logdet = 0.f;
    for (int k = 0; k < 64; k++) {
        float v = (l >= k) ? fabsf(M[l][k]) : -1.f;
        int idx = l;
        #pragma unroll
        for (int mm = 1; mm < 64; mm <<= 1) {
            const float ov = __shfl_xor(v, mm);
            const int oi = __shfl_xor(idx, mm);
            if (ov > v || (ov == v && oi < idx)) { v = ov; idx = oi; }
        }
        if (idx != k) {
            const float t1 = M[k][l], t2 = M[idx][l];
            __syncthreads();
            M[k][l] = t2;
            M[idx][l] = t1;
        }
        __syncthreads();
        const float piv = M[k][k];
        logdet += logf(fabsf(piv));
        if (l > k) {
            const float f = M[l][k] / piv;
            for (int c = k + 1; c < 64; c++) M[l][c] = fmaf(-f, M[k][c], M[l][c]);
        }
        __syncthreads();
    }
    if (l == 0) scal[3] = logdet;
}

// ---------------- final loss assembly
__global__ __launch_bounds__(256) void k_final(const float* __restrict__ GP,
    const float* __restrict__ SS, const float* __restrict__ FFt, const float* __restrict__ u_vec,
    const float* __restrict__ sizes, const float* __restrict__ deg_row,
    const float* __restrict__ AS64, const float* __restrict__ S,
    const float* __restrict__ scal, float* __restrict__ out_loss, const float fn) {
    __shared__ float red[4];
    const int t = threadIdx.x;
    float sA = 0.f, trl = 0.f, trg = 0.f, u2 = 0.f, sz2 = 0.f;
    for (int q = t; q < 4096; q += 256) sA += SS[q] * FFt[q];
    for (int q = t; q < 4096; q += 256) {
        const int i = q >> 6, c = q & 63;
        const float ls = deg_row[i] * S[i * 64 + c] - AS64[q];
        trl += ls * FFt[c * 64 + i];
    }
    if (t < 64) { trg = GP[t * 65]; u2 = u_vec[t] * u_vec[t]; sz2 = sizes[t] * sizes[t]; }
    sA = bred256(sA, red);
    trl = bred256(trl, red);
    trg = bred256(trg, red);
    u2 = bred256(u2, red);
    sz2 = bred256(sz2, red);
    if (t == 0) {
        const float m = scal[0], sumF2 = scal[1], gfp = scal[2], lad = scal[3];
        const float spectral = -(trg - u2 / (2.f * m)) / (2.f * m);
        const float collapse = sqrtf(sz2) / fn * 8.f - 1.f;
        const float frob = sqrtf(fmaxf(sA - 2.f * gfp + sumF2, 0.f)) * 1e-4f;
        const float one_two = sqrtf(sz2) * 1e-4f;
        const float smooth = lad * (-1e-4f);
        out_loss[0] = spectral + 0.1f * collapse + smooth + trl + frob + one_two;
    }
}

extern "C" void kernel_launch(void* const* d_in, const int* in_sizes, int n_in,
                              void* d_out, int out_size, void* d_ws, size_t ws_size,
                              hipStream_t stream) {
    const float* F = (const float*)d_in[0];
    const int* esrc = (const int*)d_in[1];
    const int* edst = (const int*)d_in[2];
    const float* ev = (const float*)d_in[3];
    const float* Wg = (const float*)d_in[4];
    const float* bg = (const float*)d_in[5];
    const int n = in_sizes[0] / 512;
    const int E = in_sizes[1];

    float* outF = (float*)d_out;                 // FP [64*512]
    float* outS = outF + 64 * 512;               // S [n*64]
    float* outL = outS + (size_t)n * 64;         // loss scalar

    char* w = (char*)d_ws;
    // ---- zeroed region
    float* sizes = (float*)w;                    // 64
    float* u_vec = sizes + 64;                   // 64
    float* scal = u_vec + 64;                    // 64 (m, sumF2, gfp, logabsdet)
    float* G = scal + 64;                        // 64*512
    float* GP = G + 64 * 512;                    // 4096
    float* SS = GP + 4096;                       // 4096
    float* SDS = SS + 4096;                      // 4096
    int* cnt8 = (int*)(SDS + 4096);              // 8n
    char* zend = (char*)(cnt8 + (size_t)8 * n);
    const size_t zero_bytes = (size_t)(zend - w);
    // ---- non-zeroed region
    float* deg_row = (float*)zend;               // n
    float* AS64 = deg_row + n;                   // 4096
    float* FFt = AS64 + 4096;                    // 4096
    int* cnt = (int*)(FFt + 4096);               // n
    int* blocksum = cnt + n;                     // 256
    int* blockoff = blocksum + 256;              // 256
    int* row_start = blockoff + 256;             // n+8
    int* cursor8 = row_start + n + 8;            // 8n
    u16* Sbf = (u16*)(cursor8 + (size_t)8 * n);  // n*64
    u16* ASbf = Sbf + (size_t)n * 64;            // n*64
    u16* Wt = ASbf + (size_t)n * 64;             // 64*512
    int2* sedge = (int2*)(Wt + 64 * 512);        // E

    hipMemsetAsync(d_ws, 0, zero_bytes, stream);
    k_prep<<<128, 256, 0, stream>>>(Wg, Wt);
    k_deg<<<2048, 256, 0, stream>>>(esrc, ev, E, cnt8, n, scal);
    k1<<<n / 64, 256, 0, stream>>>(F, Wt, bg, outS, Sbf, sizes, scal);
    k_merge<<<n / 256, 256, 0, stream>>>(cnt8, n, cnt, blocksum);
    k_scan2<<<1, 256, 0, stream>>>(blocksum, blockoff, row_start, n, E);
    k_scan3<<<n / 256, 256, 0, stream>>>(cnt, cnt8, blockoff, row_start, cursor8, n);
    k_scatter<<<2048, 256, 0, stream>>>(esrc, edst, ev, E, cursor8, n, sedge);
    k2m<<<512, 256, 0, stream>>>(F, Sbf, G);
    k_as<<<n / 4, 256, 0, stream>>>(row_start, sedge, Sbf, ASbf, deg_row);
    k_as64<<<64, 64, 0, stream>>>(row_start, sedge, outS, AS64);
    k_kk<<<(n / 512) * 4, 256, 0, stream>>>(Sbf, ASbf, deg_row, GP, SS, SDS, u_vec);
    k_fp<<<128, 256, 0, stream>>>(G, sizes, outF, scal);
    k_fft<<<64, 256, 0, stream>>>(outF, FFt);
    k_lu<<<1, 64, 0, stream>>>(SDS, GP, scal);
    k_final<<<1, 256, 0, stream>>>(GP, SS, FFt, u_vec, sizes, deg_row, AS64, outS, scal, outL, (float)n);
}

// Round 5
// 558.875 us; speedup vs baseline: 2.6541x; 1.5349x over previous
//
#include <hip/hip_runtime.h>
#include <hip/hip_bf16.h>
#include <cstdint>
#include <cstddef>

typedef unsigned short u16;
typedef float f32x4 __attribute__((ext_vector_type(4)));
typedef short bf16x8 __attribute__((ext_vector_type(8)));
typedef unsigned short u16x8 __attribute__((ext_vector_type(8)));

__device__ __forceinline__ u16 f2bf(float f) {
    uint32_t u = __float_as_uint(f);
    u += 0x7fffu + ((u >> 16) & 1u);
    return (u16)(u >> 16);
}
__device__ __forceinline__ float bf2f(u16 h) {
    return __uint_as_float(((uint32_t)h) << 16);
}

// ---------------- W pre-transpose + swizzle
__global__ __launch_bounds__(256) void k_prep(const float* __restrict__ Wg, u16* __restrict__ Wt) {
    int idx = blockIdx.x * 256 + threadIdx.x;   // 32768
    int k = idx >> 6, c = idx & 63;
    int lin = c * 512 + (k ^ ((c & 7) << 3));
    Wt[lin] = f2bf(Wg[idx]);
}

// ---------------- fused logits GEMM + softmax
__global__ __launch_bounds__(256) void k1(const float* __restrict__ F,
    const u16* __restrict__ WtG, const float* __restrict__ bias,
    float* __restrict__ S_out, u16* __restrict__ Sbf,
    float* __restrict__ sizes, float* __restrict__ scal) {
    __shared__ __align__(16) u16 Wl[64 * 512];
    __shared__ __align__(16) u16 Al[64 * 64];
    __shared__ float red4[4];
    const int tid = threadIdx.x;
    const int row0 = blockIdx.x * 64;
    for (int j = tid; j < 4096; j += 256)
        ((uint4*)Wl)[j] = ((const uint4*)WtG)[j];

    const int lane = tid & 63;
    const int wv = __builtin_amdgcn_readfirstlane(tid >> 6);
    const int l15 = lane & 15, lq = lane >> 4;
    f32x4 acc[4];
    #pragma unroll
    for (int tn = 0; tn < 4; tn++)
        #pragma unroll
        for (int e = 0; e < 4; e++) acc[tn][e] = 0.f;
    float sumf2 = 0.f;
    const int sr = tid >> 2, skq = tid & 3;
    const int sw = (sr & 7) << 3;

    for (int k0 = 0; k0 < 512; k0 += 64) {
        const float* fp = F + (size_t)(row0 + sr) * 512 + k0 + skq * 16;
        float4 v[4];
        u16 h[16];
        #pragma unroll
        for (int q = 0; q < 4; q++) v[q] = ((const float4*)fp)[q];
        #pragma unroll
        for (int q = 0; q < 4; q++) {
            sumf2 += v[q].x * v[q].x + v[q].y * v[q].y + v[q].z * v[q].z + v[q].w * v[q].w;
            h[q * 4 + 0] = f2bf(v[q].x); h[q * 4 + 1] = f2bf(v[q].y);
            h[q * 4 + 2] = f2bf(v[q].z); h[q * 4 + 3] = f2bf(v[q].w);
        }
        #pragma unroll
        for (int half = 0; half < 2; half++) {
            u16x8 pk;
            #pragma unroll
            for (int e2 = 0; e2 < 8; e2++) pk[e2] = h[half * 8 + e2];
            *(u16x8*)&Al[sr * 64 + ((skq * 16 + half * 8) ^ sw)] = pk;
        }
        __syncthreads();
        #pragma unroll
        for (int kk = 0; kk < 64; kk += 32) {
            const int arow = wv * 16 + l15;
            bf16x8 a = *(const bf16x8*)&Al[arow * 64 + ((kk + lq * 8) ^ ((arow & 7) << 3))];
            #pragma unroll
            for (int tn = 0; tn < 4; tn++) {
                const int bc = tn * 16 + l15;
                bf16x8 b = *(const bf16x8*)&Wl[bc * 512 + ((k0 + kk + lq * 8) ^ ((bc & 7) << 3))];
                acc[tn] = __builtin_amdgcn_mfma_f32_16x16x32_bf16(a, b, acc[tn], 0, 0, 0);
            }
        }
        __syncthreads();
    }

    float bias4[4], szacc[4] = {0.f, 0.f, 0.f, 0.f};
    #pragma unroll
    for (int tn = 0; tn < 4; tn++) bias4[tn] = bias[tn * 16 + l15];
    #pragma unroll
    for (int r2 = 0; r2 < 4; r2++) {
        float L[4];
        #pragma unroll
        for (int tn = 0; tn < 4; tn++) L[tn] = acc[tn][r2] + bias4[tn];
        float mx = fmaxf(fmaxf(L[0], L[1]), fmaxf(L[2], L[3]));
        #pragma unroll
        for (int mm = 1; mm < 16; mm <<= 1) mx = fmaxf(mx, __shfl_xor(mx, mm));
        float e[4], s = 0.f;
        #pragma unroll
        for (int tn = 0; tn < 4; tn++) { e[tn] = __expf(L[tn] - mx); s += e[tn]; }
        #pragma unroll
        for (int mm = 1; mm < 16; mm <<= 1) s += __shfl_xor(s, mm);
        const float inv = 1.f / s;
        const size_t grow = (size_t)(row0 + wv * 16 + lq * 4 + r2);
        #pragma unroll
        for (int tn = 0; tn < 4; tn++) {
            const float svl = e[tn] * inv;
            S_out[grow * 64 + tn * 16 + l15] = svl;
            Sbf[grow * 64 + tn * 16 + l15] = f2bf(svl);
            szacc[tn] += svl;
        }
    }
    #pragma unroll
    for (int tn = 0; tn < 4; tn++) {
        float vs = szacc[tn];
        vs += __shfl_xor(vs, 16);
        vs += __shfl_xor(vs, 32);
        if (lq == 0) atomicAdd(sizes + tn * 16 + l15, vs);
    }
    #pragma unroll
    for (int mm = 1; mm < 64; mm <<= 1) sumf2 += __shfl_xor(sumf2, mm);
    if (lane == 0) red4[wv] = sumf2;
    __syncthreads();
    if (tid == 0) atomicAdd(scal + 1, red4[0] + red4[1] + red4[2] + red4[3]);
}

// ---------------- k_sweep: one pass over the unsorted edge list.
// Per 64-edge chunk: stage P[e][c]=v*S[t_e][c], Q[e][c]=S[s_e][c] into LDS
// (pair-packed swizzled K-major, same layout as k2m), MFMA GP += P^T Q.
// Folds in: deg8 histogram (XCD-private), m, AS64 (rare s<64, f32 exact).
__global__ __launch_bounds__(512) void k_sweep(const int* __restrict__ esrc,
    const int* __restrict__ edst, const float* __restrict__ ev,
    const u16* __restrict__ Sbf, const float* __restrict__ S, const int E,
    float* __restrict__ GP8, float* __restrict__ deg8, const int n,
    float* __restrict__ AS64, float* __restrict__ scal) {
    __shared__ uint32_t Pl[64 * 32];
    __shared__ uint32_t Ql[64 * 32];
    const int tid = threadIdx.x;
    const int lane = tid & 63;
    const int wv = __builtin_amdgcn_readfirstlane(tid >> 6);
    const int l15 = lane & 15, lq = lane >> 4;
    const int xcd = blockIdx.x & 7;
    float* __restrict__ degmy = deg8 + (size_t)xcd * n;
    float* __restrict__ GPmy = GP8 + (size_t)xcd * 4096;

    const bool isP = tid < 256;
    const int st = tid & 255;
    const int p = st >> 3;            // edge-pair 0..31
    const int g = st & 7;             // col group (8 cols)
    float vsum = 0.f;

    f32x4 acc[2];
    #pragma unroll
    for (int t = 0; t < 2; t++)
        #pragma unroll
        for (int r = 0; r < 4; r++) acc[t][r] = 0.f;

    const int ma = 16 * (wv & 3) + l15;
    const int aoff = ma * 32;
    const int aswz = ((ma >> 2) & 7) << 2;
    const int nb0 = 32 * (wv >> 2) + l15;
    const int nb1 = nb0 + 16;
    const int b0off = nb0 * 32, b0swz = ((nb0 >> 2) & 7) << 2;
    const int b1off = nb1 * 32, b1swz = ((nb1 >> 2) & 7) << 2;

    const int nchunks = E >> 6;
    for (int ch = blockIdx.x; ch < nchunks; ch += gridDim.x) {
        const int base = ch << 6;
        const int e0 = base + 2 * p;
        if (isP) {
            const int2 tt = *(const int2*)&edst[e0];
            const float2 vv = *(const float2*)&ev[e0];
            const u16x8 a = *(const u16x8*)&Sbf[(size_t)tt.x * 64 + 8 * g];
            const u16x8 b = *(const u16x8*)&Sbf[(size_t)tt.y * 64 + 8 * g];
            #pragma unroll
            for (int j = 0; j < 8; j++) {
                const int c = 8 * g + j;
                const uint32_t pk = (uint32_t)f2bf(vv.x * bf2f((u16)a[j])) |
                                    ((uint32_t)f2bf(vv.y * bf2f((u16)b[j])) << 16);
                Pl[c * 32 + (p ^ (((c >> 2) & 7) << 2))] = pk;
            }
        } else {
            const int2 ss = *(const int2*)&esrc[e0];
            const u16x8 a = *(const u16x8*)&Sbf[(size_t)ss.x * 64 + 8 * g];
            const u16x8 b = *(const u16x8*)&Sbf[(size_t)ss.y * 64 + 8 * g];
            #pragma unroll
            for (int j = 0; j < 8; j++) {
                const int c = 8 * g + j;
                const uint32_t pk = (uint32_t)(u16)a[j] | ((uint32_t)(u16)b[j] << 16);
                Ql[c * 32 + (p ^ (((c >> 2) & 7) << 2))] = pk;
            }
            if (g == 0) {
                const float2 vv = *(const float2*)&ev[e0];
                vsum += vv.x + vv.y;
                atomicAdd(degmy + ss.x, vv.x);
                atomicAdd(degmy + ss.y, vv.y);
            }
            if (ss.x < 64) {
                const float v0 = ev[e0];
                const int t0 = edst[e0];
                const float4 fa = *(const float4*)(S + (size_t)t0 * 64 + 8 * g);
                const float4 fb = *(const float4*)(S + (size_t)t0 * 64 + 8 * g + 4);
                float* dst = AS64 + ss.x * 64 + 8 * g;
                atomicAdd(dst + 0, v0 * fa.x); atomicAdd(dst + 1, v0 * fa.y);
                atomicAdd(dst + 2, v0 * fa.z); atomicAdd(dst + 3, v0 * fa.w);
                atomicAdd(dst + 4, v0 * fb.x); atomicAdd(dst + 5, v0 * fb.y);
                atomicAdd(dst + 6, v0 * fb.z); atomicAdd(dst + 7, v0 * fb.w);
            }
            if (ss.y < 64) {
                const float v1 = ev[e0 + 1];
                const int t1 = edst[e0 + 1];
                const float4 fa = *(const float4*)(S + (size_t)t1 * 64 + 8 * g);
                const float4 fb = *(const float4*)(S + (size_t)t1 * 64 + 8 * g + 4);
                float* dst = AS64 + ss.y * 64 + 8 * g;
                atomicAdd(dst + 0, v1 * fa.x); atomicAdd(dst + 1, v1 * fa.y);
                atomicAdd(dst + 2, v1 * fa.z); atomicAdd(dst + 3, v1 * fa.w);
                atomicAdd(dst + 4, v1 * fb.x); atomicAdd(dst + 5, v1 * fb.y);
                atomicAdd(dst + 6, v1 * fb.z); atomicAdd(dst + 7, v1 * fb.w);
            }
        }
        __syncthreads();
        #pragma unroll
        for (int kk = 0; kk < 64; kk += 32) {
            const int w0 = (kk >> 1) + (lq << 2);
            const bf16x8 af = *(const bf16x8*)&Pl[aoff + (w0 ^ aswz)];
            const bf16x8 bf0 = *(const bf16x8*)&Ql[b0off + (w0 ^ b0swz)];
            const bf16x8 bf1 = *(const bf16x8*)&Ql[b1off + (w0 ^ b1swz)];
            acc[0] = __builtin_amdgcn_mfma_f32_16x16x32_bf16(af, bf0, acc[0], 0, 0, 0);
            acc[1] = __builtin_amdgcn_mfma_f32_16x16x32_bf16(af, bf1, acc[1], 0, 0, 0);
        }
        __syncthreads();
    }
    // epilogue: GP partials (XCD-private copy)
    #pragma unroll
    for (int t = 0; t < 2; t++)
        #pragma unroll
        for (int r = 0; r < 4; r++) {
            const int c1 = 16 * (wv & 3) + 4 * lq + r;
            const int c2 = 32 * (wv >> 2) + 16 * t + l15;
            atomicAdd(GPmy + c1 * 64 + c2, acc[t][r]);
        }
    if (wv >= 4) {
        #pragma unroll
        for (int mm = 1; mm < 64; mm <<= 1) vsum += __shfl_xor(vsum, mm);
        if (lane == 0) atomicAdd(scal + 0, vsum);
    }
}

// ---------------- merge deg8 -> deg_row, GP8 -> GP
__global__ __launch_bounds__(256) void k_mrg(const float* __restrict__ deg8,
    const float* __restrict__ GP8, const int n, float* __restrict__ deg_row,
    float* __restrict__ GP) {
    const int bid = blockIdx.x;
    const int t = threadIdx.x;
    if (bid < 256) {
        const int i = bid * 256 + t;
        float s = 0.f;
        #pragma unroll
        for (int c = 0; c < 8; c++) s += deg8[(size_t)c * n + i];
        deg_row[i] = s;
    } else {
        const int j = (bid - 256) * 256 + t;
        float s = 0.f;
        #pragma unroll
        for (int c = 0; c < 8; c++) s += GP8[(size_t)c * 4096 + j];
        GP[j] = s;
    }
}

// ---------------- k2m: G = S^T F via MFMA
__global__ __launch_bounds__(256) void k2m(const float* __restrict__ F,
    const u16* __restrict__ Sbf, float* __restrict__ G) {
    __shared__ uint32_t Ss[64 * 32];
    __shared__ uint32_t Fs[128 * 32];
    const int tid = threadIdx.x;
    const int lane = tid & 63;
    const int wv = __builtin_amdgcn_readfirstlane(tid >> 6);
    const int l15 = lane & 15, lq = lane >> 4;
    const int d0 = (blockIdx.x & 3) * 128;
    const int kblk = blockIdx.x >> 2;

    f32x4 acc[8];
    #pragma unroll
    for (int t8 = 0; t8 < 8; t8++)
        #pragma unroll
        for (int r = 0; r < 4; r++) acc[t8][r] = 0.f;

    const int s_ip = tid >> 3;
    const int s_cs = (tid & 7) * 8;
    const int f_dg = tid & 31;
    const int f_ipb = tid >> 5;

    for (int ch = 0; ch < 8; ch++) {
        const int i0 = kblk * 512 + ch * 64;
        {
            const u16x8 r0 = *(const u16x8*)&Sbf[(size_t)(i0 + 2 * s_ip) * 64 + s_cs];
            const u16x8 r1 = *(const u16x8*)&Sbf[(size_t)(i0 + 2 * s_ip + 1) * 64 + s_cs];
            #pragma unroll
            for (int j = 0; j < 8; j++) {
                const int c = s_cs + j;
                const uint32_t pk = (uint32_t)(u16)r0[j] | ((uint32_t)(u16)r1[j] << 16);
                Ss[c * 32 + (s_ip ^ (((c >> 2) & 7) << 2))] = pk;
            }
        }
        #pragma unroll
        for (int s = 0; s < 4; s++) {
            const int ip = f_ipb + 8 * s;
            const float4 a = *(const float4*)(F + (size_t)(i0 + 2 * ip) * 512 + d0 + 4 * f_dg);
            const float4 b = *(const float4*)(F + (size_t)(i0 + 2 * ip + 1) * 512 + d0 + 4 * f_dg);
            const float al[4] = {a.x, a.y, a.z, a.w};
            const float bl[4] = {b.x, b.y, b.z, b.w};
            #pragma unroll
            for (int j = 0; j < 4; j++) {
                const int d = 4 * f_dg + j;
                const uint32_t pk = (uint32_t)f2bf(al[j]) | ((uint32_t)f2bf(bl[j]) << 16);
                Fs[d * 32 + (ip ^ (((d >> 2) & 7) << 2))] = pk;
            }
        }
        __syncthreads();
        #pragma unroll
        for (int kk = 0; kk < 64; kk += 32) {
            const int w0 = (kk >> 1) + (lq << 2);
            const int ca = 16 * wv + l15;
            const bf16x8 afrag = *(const bf16x8*)&Ss[ca * 32 + (w0 ^ (((ca >> 2) & 7) << 2))];
            #pragma unroll
            for (int t8 = 0; t8 < 8; t8++) {
                const int d = 16 * t8 + l15;
                const bf16x8 bfrag = *(const bf16x8*)&Fs[d * 32 + (w0 ^ (((d >> 2) & 7) << 2))];
                acc[t8] = __builtin_amdgcn_mfma_f32_16x16x32_bf16(afrag, bfrag, acc[t8], 0, 0, 0);
            }
        }
        __syncthreads();
    }
    #pragma unroll
    for (int t8 = 0; t8 < 8; t8++) {
        #pragma unroll
        for (int r = 0; r < 4; r++) {
            const int c = 16 * wv + 4 * lq + r;
            const int d = d0 + 16 * t8 + l15;
            atomicAdd(G + (size_t)c * 512 + d, acc[t8][r]);
        }
    }
}

// ---------------- fused k x k reductions: SS=S^T S, SDS=(deg.S)^T S, u=S^T deg
__global__ __launch_bounds__(256) void k_kk(const u16* __restrict__ Sbf,
    const float* __restrict__ deg_row, float* __restrict__ SS,
    float* __restrict__ SDS, float* __restrict__ u_vec) {
    __shared__ float Pss[4][16][64];
    __shared__ float Psds[4][16][64];
    __shared__ float Pu[4][64];
    const int tid = threadIdx.x, lane = tid & 63;
    const int wv = __builtin_amdgcn_readfirstlane(tid >> 6);
    const int cs = blockIdx.x & 3, c0 = cs * 16;
    const int rbase = (blockIdx.x >> 2) * 512 + wv * 128;
    float ss[16], sds[16], ua = 0.f;
    #pragma unroll
    for (int cc = 0; cc < 16; cc++) { ss[cc] = 0.f; sds[cc] = 0.f; }
    for (int r = 0; r < 128; r++) {
        const int i = rbase + r;
        const float sv = bf2f(Sbf[(size_t)i * 64 + lane]);
        const float dr = deg_row[i];
        ua = fmaf(dr, sv, ua);
        const u16* srow = Sbf + (size_t)i * 64 + c0;
        #pragma unroll
        for (int cc = 0; cc < 16; cc++) {
            const float sc = bf2f(srow[cc]);
            ss[cc] = fmaf(sc, sv, ss[cc]);
            sds[cc] = fmaf(sc * dr, sv, sds[cc]);
        }
    }
    #pragma unroll
    for (int cc = 0; cc < 16; cc++) {
        Pss[wv][cc][lane] = ss[cc]; Psds[wv][cc][lane] = sds[cc];
    }
    Pu[wv][lane] = ua;
    __syncthreads();
    for (int q = 0; q < 4; q++) {
        const int cell = tid * 4 + q, cc = cell >> 6, l = cell & 63;
        atomicAdd(SS + (c0 + cc) * 64 + l, Pss[0][cc][l] + Pss[1][cc][l] + Pss[2][cc][l] + Pss[3][cc][l]);
        atomicAdd(SDS + (c0 + cc) * 64 + l, Psds[0][cc][l] + Psds[1][cc][l] + Psds[2][cc][l] + Psds[3][cc][l]);
    }
    if (cs == 0 && tid < 64)
        atomicAdd(u_vec + tid, Pu[0][tid] + Pu[1][tid] + Pu[2][tid] + Pu[3][tid]);
}

__device__ __forceinline__ float bred256(float v, float* red) {
    #pragma unroll
    for (int mm = 1; mm < 64; mm <<= 1) v += __shfl_xor(v, mm);
    const int t = threadIdx.x;
    __syncthreads();
    if ((t & 63) == 0) red[t >> 6] = v;
    __syncthreads();
    return red[0] + red[1] + red[2] + red[3];
}

// ---------------- FP = selu(G/sizes) + <G,FP>
__global__ __launch_bounds__(256) void k_fp(const float* __restrict__ G,
    const float* __restrict__ sizes, float* __restrict__ FP, float* __restrict__ scal) {
    __shared__ float red[4];
    const int idx = blockIdx.x * 256 + threadIdx.x;
    const int c = idx >> 9;
    const float g = G[idx];
    const float x = g / sizes[c];
    const float fp = 1.0507009873554805f * (x > 0.f ? x : 1.6732632423543772f * (__expf(x) - 1.f));
    FP[idx] = fp;
    const float gd = bred256(g * fp, red);
    if (threadIdx.x == 0) atomicAdd(scal + 2, gd);
}

// ---------------- FFt = FP FP^T
__global__ __launch_bounds__(256) void k_fft(const float* __restrict__ FP, float* __restrict__ FFt) {
    __shared__ float red[256];
    const int c = blockIdx.x;
    const int cp = threadIdx.x & 63, part = threadIdx.x >> 6;
    float a = 0.f;
    const int dbase = part * 128;
    for (int dd = 0; dd < 128; dd++)
        a = fmaf(FP[c * 512 + dbase + dd], FP[cp * 512 + dbase + dd], a);
    red[threadIdx.x] = a;
    __syncthreads();
    if (threadIdx.x < 64)
        FFt[c * 64 + threadIdx.x] = red[threadIdx.x] + red[threadIdx.x + 64] +
                                    red[threadIdx.x + 128] + red[threadIdx.x + 192];
}

// ---------------- logabsdet(StLS + 1) via LU
__global__ __launch_bounds__(64) void k_lu(const float* __restrict__ SDS,
    const float* __restrict__ GP, float* __restrict__ scal) {
    __shared__ float M[64][65];
    const int l = threadIdx.x;
    for (int c = 0; c < 64; c++) M[l][c] = SDS[l * 64 + c] - GP[l * 64 + c] + 1.0f;
    __syncthreads();
    float logdet = 0.f;
    for (int k = 0; k < 64; k++) {
        float v = (l >= k) ? fabsf(M[l][k]) : -1.f;
        int idx = l;
        #pragma unroll
        for (int mm = 1; mm < 64; mm <<= 1) {
            const float ov = __shfl_xor(v, mm);
            const int oi = __shfl_xor(idx, mm);
            if (ov > v || (ov == v && oi < idx)) { v = ov; idx = oi; }
        }
        if (idx != k) {
            const float t1 = M[k][l], t2 = M[idx][l];
            __syncthreads();
            M[k][l] = t2;
            M[idx][l] = t1;
        }
        __syncthreads();
        const float piv = M[k][k];
        logdet += logf(fabsf(piv));
        if (l > k) {
            const float f = M[l][k] / piv;
            for (int c = k + 1; c < 64; c++) M[l][c] = fmaf(-f, M[k][c], M[l][c]);
        }
        __syncthreads();
    }
    if (l == 0) scal[3] = logdet;
}

// ---------------- final loss assembly
__global__ __launch_bounds__(256) void k_final(const float* __restrict__ GP,
    const float* __restrict__ SS, const float* __restrict__ FFt, const float* __restrict__ u_vec,
    const float* __restrict__ sizes, const float* __restrict__ deg_row,
    const float* __restrict__ AS64, const float* __restrict__ S,
    const float* __restrict__ scal, float* __restrict__ out_loss, const float fn) {
    __shared__ float red[4];
    const int t = threadIdx.x;
    float sA = 0.f, trl = 0.f, trg = 0.f, u2 = 0.f, sz2 = 0.f;
    for (int q = t; q < 4096; q += 256) sA += SS[q] * FFt[q];
    for (int q = t; q < 4096; q += 256) {
        const int i = q >> 6, c = q & 63;
        const float ls = deg_row[i] * S[i * 64 + c] - AS64[q];
        trl += ls * FFt[c * 64 + i];
    }
    if (t < 64) { trg = GP[t * 65]; u2 = u_vec[t] * u_vec[t]; sz2 = sizes[t] * sizes[t]; }
    sA = bred256(sA, red);
    trl = bred256(trl, red);
    trg = bred256(trg, red);
    u2 = bred256(u2, red);
    sz2 = bred256(sz2, red);
    if (t == 0) {
        const float m = scal[0], sumF2 = scal[1], gfp = scal[2], lad = scal[3];
        const float spectral = -(trg - u2 / (2.f * m)) / (2.f * m);
        const float collapse = sqrtf(sz2) / fn * 8.f - 1.f;
        const float frob = sqrtf(fmaxf(sA - 2.f * gfp + sumF2, 0.f)) * 1e-4f;
        const float one_two = sqrtf(sz2) * 1e-4f;
        const float smooth = lad * (-1e-4f);
        out_loss[0] = spectral + 0.1f * collapse + smooth + trl + frob + one_two;
    }
}

extern "C" void kernel_launch(void* const* d_in, const int* in_sizes, int n_in,
                              void* d_out, int out_size, void* d_ws, size_t ws_size,
                              hipStream_t stream) {
    const float* F = (const float*)d_in[0];
    const int* esrc = (const int*)d_in[1];
    const int* edst = (const int*)d_in[2];
    const float* ev = (const float*)d_in[3];
    const float* Wg = (const float*)d_in[4];
    const float* bg = (const float*)d_in[5];
    const int n = in_sizes[0] / 512;
    const int E = in_sizes[1];

    float* outF = (float*)d_out;                 // FP [64*512]
    float* outS = outF + 64 * 512;               // S [n*64]
    float* outL = outS + (size_t)n * 64;         // loss scalar

    char* w = (char*)d_ws;
    // ---- zeroed region
    float* sizes = (float*)w;                    // 64
    float* u_vec = sizes + 64;                   // 64
    float* scal = u_vec + 64;                    // 64 (m, sumF2, gfp, logabsdet)
    float* G = scal + 64;                        // 64*512
    float* GP = G + 64 * 512;                    // 4096
    float* SS = GP + 4096;                       // 4096
    float* SDS = SS + 4096;                      // 4096
    float* AS64 = SDS + 4096;                    // 4096
    float* GP8 = AS64 + 4096;                    // 8*4096
    float* deg8 = GP8 + 8 * 4096;                // 8n
    char* zend = (char*)(deg8 + (size_t)8 * n);
    const size_t zero_bytes = (size_t)(zend - w);
    // ---- non-zeroed region
    float* deg_row = (float*)zend;               // n
    float* FFt = deg_row + n;                    // 4096
    u16* Sbf = (u16*)(FFt + 4096);               // n*64
    u16* Wt = Sbf + (size_t)n * 64;              // 64*512

    hipMemsetAsync(d_ws, 0, zero_bytes, stream);
    k_prep<<<128, 256, 0, stream>>>(Wg, Wt);
    k1<<<n / 64, 256, 0, stream>>>(F, Wt, bg, outS, Sbf, sizes, scal);
    k_sweep<<<1024, 512, 0, stream>>>(esrc, edst, ev, Sbf, outS, E, GP8, deg8, n, AS64, scal);
    k2m<<<512, 256, 0, stream>>>(F, Sbf, G);
    k_mrg<<<272, 256, 0, stream>>>(deg8, GP8, n, deg_row, GP);
    k_kk<<<(n / 512) * 4, 256, 0, stream>>>(Sbf, deg_row, SS, SDS, u_vec);
    k_fp<<<128, 256, 0, stream>>>(G, sizes, outF, scal);
    k_fft<<<64, 256, 0, stream>>>(outF, FFt);
    k_lu<<<1, 64, 0, stream>>>(SDS, GP, scal);
    k_final<<<1, 256, 0, stream>>>(GP, SS, FFt, u_vec, sizes, deg_row, AS64, outS, scal, outL, (float)n);
}

// Round 6
// 544.995 us; speedup vs baseline: 2.7217x; 1.0255x over previous
//
#include <hip/hip_runtime.h>
#include <hip/hip_bf16.h>
#include <cstdint>
#include <cstddef>

typedef unsigned short u16;
typedef float f32x4 __attribute__((ext_vector_type(4)));
typedef short bf16x8 __attribute__((ext_vector_type(8)));
typedef unsigned short u16x8 __attribute__((ext_vector_type(8)));

__device__ __forceinline__ u16 f2bf(float f) {
    uint32_t u = __float_as_uint(f);
    u += 0x7fffu + ((u >> 16) & 1u);
    return (u16)(u >> 16);
}
__device__ __forceinline__ float bf2f(u16 h) {
    return __uint_as_float(((uint32_t)h) << 16);
}

// conflict-free word swizzle for [64 rows][32 words] pair-packed tiles:
// reads spread via c&7, writes spread via c>>3.
#define SWZ(c) ((((c) ^ ((c) >> 3)) & 7) << 2)

// ---------------- W pre-transpose + swizzle
__global__ __launch_bounds__(256) void k_prep(const float* __restrict__ Wg, u16* __restrict__ Wt) {
    int idx = blockIdx.x * 256 + threadIdx.x;   // 32768
    int k = idx >> 6, c = idx & 63;
    int lin = c * 512 + (k ^ ((c & 7) << 3));
    Wt[lin] = f2bf(Wg[idx]);
}

// ---------------- fused logits GEMM + softmax
__global__ __launch_bounds__(256) void k1(const float* __restrict__ F,
    const u16* __restrict__ WtG, const float* __restrict__ bias,
    float* __restrict__ S_out, u16* __restrict__ Sbf,
    float* __restrict__ sizes, float* __restrict__ scal) {
    __shared__ __align__(16) u16 Wl[64 * 512];
    __shared__ __align__(16) u16 Al[64 * 64];
    __shared__ float red4[4];
    const int tid = threadIdx.x;
    const int row0 = blockIdx.x * 64;
    for (int j = tid; j < 4096; j += 256)
        ((uint4*)Wl)[j] = ((const uint4*)WtG)[j];

    const int lane = tid & 63;
    const int wv = __builtin_amdgcn_readfirstlane(tid >> 6);
    const int l15 = lane & 15, lq = lane >> 4;
    f32x4 acc[4];
    #pragma unroll
    for (int tn = 0; tn < 4; tn++)
        #pragma unroll
        for (int e = 0; e < 4; e++) acc[tn][e] = 0.f;
    float sumf2 = 0.f;
    const int sr = tid >> 2, skq = tid & 3;
    const int sw = (sr & 7) << 3;

    for (int k0 = 0; k0 < 512; k0 += 64) {
        const float* fp = F + (size_t)(row0 + sr) * 512 + k0 + skq * 16;
        float4 v[4];
        u16 h[16];
        #pragma unroll
        for (int q = 0; q < 4; q++) v[q] = ((const float4*)fp)[q];
        #pragma unroll
        for (int q = 0; q < 4; q++) {
            sumf2 += v[q].x * v[q].x + v[q].y * v[q].y + v[q].z * v[q].z + v[q].w * v[q].w;
            h[q * 4 + 0] = f2bf(v[q].x); h[q * 4 + 1] = f2bf(v[q].y);
            h[q * 4 + 2] = f2bf(v[q].z); h[q * 4 + 3] = f2bf(v[q].w);
        }
        #pragma unroll
        for (int half = 0; half < 2; half++) {
            u16x8 pk;
            #pragma unroll
            for (int e2 = 0; e2 < 8; e2++) pk[e2] = h[half * 8 + e2];
            *(u16x8*)&Al[sr * 64 + ((skq * 16 + half * 8) ^ sw)] = pk;
        }
        __syncthreads();
        #pragma unroll
        for (int kk = 0; kk < 64; kk += 32) {
            const int arow = wv * 16 + l15;
            bf16x8 a = *(const bf16x8*)&Al[arow * 64 + ((kk + lq * 8) ^ ((arow & 7) << 3))];
            #pragma unroll
            for (int tn = 0; tn < 4; tn++) {
                const int bc = tn * 16 + l15;
                bf16x8 b = *(const bf16x8*)&Wl[bc * 512 + ((k0 + kk + lq * 8) ^ ((bc & 7) << 3))];
                acc[tn] = __builtin_amdgcn_mfma_f32_16x16x32_bf16(a, b, acc[tn], 0, 0, 0);
            }
        }
        __syncthreads();
    }

    float bias4[4], szacc[4] = {0.f, 0.f, 0.f, 0.f};
    #pragma unroll
    for (int tn = 0; tn < 4; tn++) bias4[tn] = bias[tn * 16 + l15];
    #pragma unroll
    for (int r2 = 0; r2 < 4; r2++) {
        float L[4];
        #pragma unroll
        for (int tn = 0; tn < 4; tn++) L[tn] = acc[tn][r2] + bias4[tn];
        float mx = fmaxf(fmaxf(L[0], L[1]), fmaxf(L[2], L[3]));
        #pragma unroll
        for (int mm = 1; mm < 16; mm <<= 1) mx = fmaxf(mx, __shfl_xor(mx, mm));
        float e[4], s = 0.f;
        #pragma unroll
        for (int tn = 0; tn < 4; tn++) { e[tn] = __expf(L[tn] - mx); s += e[tn]; }
        #pragma unroll
        for (int mm = 1; mm < 16; mm <<= 1) s += __shfl_xor(s, mm);
        const float inv = 1.f / s;
        const size_t grow = (size_t)(row0 + wv * 16 + lq * 4 + r2);
        #pragma unroll
        for (int tn = 0; tn < 4; tn++) {
            const float svl = e[tn] * inv;
            S_out[grow * 64 + tn * 16 + l15] = svl;
            Sbf[grow * 64 + tn * 16 + l15] = f2bf(svl);
            szacc[tn] += svl;
        }
    }
    #pragma unroll
    for (int tn = 0; tn < 4; tn++) {
        float vs = szacc[tn];
        vs += __shfl_xor(vs, 16);
        vs += __shfl_xor(vs, 32);
        if (lq == 0) atomicAdd(sizes + tn * 16 + l15, vs);
    }
    #pragma unroll
    for (int mm = 1; mm < 64; mm <<= 1) sumf2 += __shfl_xor(sumf2, mm);
    if (lane == 0) red4[wv] = sumf2;
    __syncthreads();
    if (tid == 0) atomicAdd(scal + 1, red4[0] + red4[1] + red4[2] + red4[3]);
}

// ---------------- k_sweep: one pass over the DIRECTED half of the edge list.
// GP partial M = sum_e v*S[t]⊗S[s]; symmetrized (M+M^T) in k_mrg.
// Double-buffered LDS, one barrier/iter, issue-early loads (T14).
__global__ __launch_bounds__(512) void k_sweep(const int* __restrict__ esrc,
    const int* __restrict__ edst, const float* __restrict__ ev,
    const u16* __restrict__ Sbf, const float* __restrict__ S, const int E2,
    float* __restrict__ GP8, float* __restrict__ deg8, const int n,
    float* __restrict__ AS64, float* __restrict__ scal) {
    __shared__ uint32_t Pl[2][64 * 32];
    __shared__ uint32_t Ql[2][64 * 32];
    const int tid = threadIdx.x;
    const int lane = tid & 63;
    const int wv = __builtin_amdgcn_readfirstlane(tid >> 6);
    const int l15 = lane & 15, lq = lane >> 4;
    const int xcd = blockIdx.x & 7;
    float* __restrict__ degmy = deg8 + (size_t)xcd * n;
    float* __restrict__ GPmy = GP8 + (size_t)xcd * 4096;

    const bool isP = tid < 256;
    const int st = tid & 255;
    const int p = st >> 3;            // edge-pair 0..31
    const int g = st & 7;             // col group (8 cols)
    float vsum = 0.f;

    f32x4 acc[2];
    #pragma unroll
    for (int t = 0; t < 2; t++)
        #pragma unroll
        for (int r = 0; r < 4; r++) acc[t][r] = 0.f;

    const int ma = 16 * (wv & 3) + l15;
    const int aoff = ma * 32, aswz = SWZ(ma);
    const int nb0 = 32 * (wv >> 2) + l15;
    const int nb1 = nb0 + 16;
    const int b0off = nb0 * 32, b0swz = SWZ(nb0);
    const int b1off = nb1 * 32, b1swz = SWZ(nb1);

    const int nch = E2 >> 6;
    const int stride = gridDim.x;
    int ch = blockIdx.x;
    if (ch >= nch) return;

    // ---- prologue: load chunk ch (indices + gathers)
    int2 ia_c, ib_c = make_int2(0, 0);
    float2 vv_c;
    {
        const int e0 = (ch << 6) + 2 * p;
        if (isP) {
            ia_c = *(const int2*)&edst[e0];
            vv_c = *(const float2*)&ev[e0];
        } else {
            ia_c = *(const int2*)&esrc[e0];
            ib_c = *(const int2*)&edst[e0];
            vv_c = *(const float2*)&ev[e0];
        }
    }
    u16x8 ra_c = *(const u16x8*)&Sbf[(size_t)ia_c.x * 64 + 8 * g];
    u16x8 rb_c = *(const u16x8*)&Sbf[(size_t)ia_c.y * 64 + 8 * g];

    int buf = 0;
    while (true) {
        uint32_t* __restrict__ Pb = &Pl[buf][0];
        uint32_t* __restrict__ Qb = &Ql[buf][0];
        // ---- write LDS from current regs
        if (isP) {
            #pragma unroll
            for (int j = 0; j < 8; j++) {
                const int c = 8 * g + j;
                const uint32_t pk = (uint32_t)f2bf(vv_c.x * bf2f((u16)ra_c[j])) |
                                    ((uint32_t)f2bf(vv_c.y * bf2f((u16)rb_c[j])) << 16);
                Pb[c * 32 + (p ^ SWZ(c))] = pk;
            }
        } else {
            #pragma unroll
            for (int j = 0; j < 8; j++) {
                const int c = 8 * g + j;
                const uint32_t pk = (uint32_t)(u16)ra_c[j] | ((uint32_t)(u16)rb_c[j] << 16);
                Qb[c * 32 + (p ^ SWZ(c))] = pk;
            }
            if (g == 0) {
                vsum += vv_c.x + vv_c.y;
                atomicAdd(degmy + ia_c.x, vv_c.x);
                atomicAdd(degmy + ia_c.y, vv_c.y);
                atomicAdd(degmy + ib_c.x, vv_c.x);
                atomicAdd(degmy + ib_c.y, vv_c.y);
            }
            // AS64 rare paths (f32 exact): AS[s] += v S[t]; AS[t] += v S[s]
            if (ia_c.x < 64) {
                const float4 fa = *(const float4*)(S + (size_t)ib_c.x * 64 + 8 * g);
                const float4 fb = *(const float4*)(S + (size_t)ib_c.x * 64 + 8 * g + 4);
                float* dst = AS64 + ia_c.x * 64 + 8 * g;
                atomicAdd(dst + 0, vv_c.x * fa.x); atomicAdd(dst + 1, vv_c.x * fa.y);
                atomicAdd(dst + 2, vv_c.x * fa.z); atomicAdd(dst + 3, vv_c.x * fa.w);
                atomicAdd(dst + 4, vv_c.x * fb.x); atomicAdd(dst + 5, vv_c.x * fb.y);
                atomicAdd(dst + 6, vv_c.x * fb.z); atomicAdd(dst + 7, vv_c.x * fb.w);
            }
            if (ia_c.y < 64) {
                const float4 fa = *(const float4*)(S + (size_t)ib_c.y * 64 + 8 * g);
                const float4 fb = *(const float4*)(S + (size_t)ib_c.y * 64 + 8 * g + 4);
                float* dst = AS64 + ia_c.y * 64 + 8 * g;
                atomicAdd(dst + 0, vv_c.y * fa.x); atomicAdd(dst + 1, vv_c.y * fa.y);
                atomicAdd(dst + 2, vv_c.y * fa.z); atomicAdd(dst + 3, vv_c.y * fa.w);
                atomicAdd(dst + 4, vv_c.y * fb.x); atomicAdd(dst + 5, vv_c.y * fb.y);
                atomicAdd(dst + 6, vv_c.y * fb.z); atomicAdd(dst + 7, vv_c.y * fb.w);
            }
            if (ib_c.x < 64) {
                const float4 fa = *(const float4*)(S + (size_t)ia_c.x * 64 + 8 * g);
                const float4 fb = *(const float4*)(S + (size_t)ia_c.x * 64 + 8 * g + 4);
                float* dst = AS64 + ib_c.x * 64 + 8 * g;
                atomicAdd(dst + 0, vv_c.x * fa.x); atomicAdd(dst + 1, vv_c.x * fa.y);
                atomicAdd(dst + 2, vv_c.x * fa.z); atomicAdd(dst + 3, vv_c.x * fa.w);
                atomicAdd(dst + 4, vv_c.x * fb.x); atomicAdd(dst + 5, vv_c.x * fb.y);
                atomicAdd(dst + 6, vv_c.x * fb.z); atomicAdd(dst + 7, vv_c.x * fb.w);
            }
            if (ib_c.y < 64) {
                const float4 fa = *(const float4*)(S + (size_t)ia_c.y * 64 + 8 * g);
                const float4 fb = *(const float4*)(S + (size_t)ia_c.y * 64 + 8 * g + 4);
                float* dst = AS64 + ib_c.y * 64 + 8 * g;
                atomicAdd(dst + 0, vv_c.y * fa.x); atomicAdd(dst + 1, vv_c.y * fa.y);
                atomicAdd(dst + 2, vv_c.y * fa.z); atomicAdd(dst + 3, vv_c.y * fa.w);
                atomicAdd(dst + 4, vv_c.y * fb.x); atomicAdd(dst + 5, vv_c.y * fb.y);
                atomicAdd(dst + 6, vv_c.y * fb.z); atomicAdd(dst + 7, vv_c.y * fb.w);
            }
        }
        // ---- issue next chunk's loads (results consumed next iteration)
        const int chn = ch + stride;
        const int chc = chn < nch ? chn : (nch - 1);
        int2 ia_n, ib_n = make_int2(0, 0);
        float2 vv_n;
        {
            const int e0 = (chc << 6) + 2 * p;
            if (isP) {
                ia_n = *(const int2*)&edst[e0];
                vv_n = *(const float2*)&ev[e0];
            } else {
                ia_n = *(const int2*)&esrc[e0];
                ib_n = *(const int2*)&edst[e0];
                vv_n = *(const float2*)&ev[e0];
            }
        }
        const u16x8 ra_n = *(const u16x8*)&Sbf[(size_t)ia_n.x * 64 + 8 * g];
        const u16x8 rb_n = *(const u16x8*)&Sbf[(size_t)ia_n.y * 64 + 8 * g];
        __syncthreads();
        // ---- MFMA on buf
        #pragma unroll
        for (int kk = 0; kk < 64; kk += 32) {
            const int w0 = (kk >> 1) + (lq << 2);
            const bf16x8 af = *(const bf16x8*)&Pb[aoff + (w0 ^ aswz)];
            const bf16x8 bf0 = *(const bf16x8*)&Qb[b0off + (w0 ^ b0swz)];
            const bf16x8 bf1 = *(const bf16x8*)&Qb[b1off + (w0 ^ b1swz)];
            acc[0] = __builtin_amdgcn_mfma_f32_16x16x32_bf16(af, bf0, acc[0], 0, 0, 0);
            acc[1] = __builtin_amdgcn_mfma_f32_16x16x32_bf16(af, bf1, acc[1], 0, 0, 0);
        }
        ch = chn;
        if (ch >= nch) break;
        ia_c = ia_n; ib_c = ib_n; vv_c = vv_n; ra_c = ra_n; rb_c = rb_n;
        buf ^= 1;
    }
    // ---- epilogue: M partials (XCD-private copy)
    #pragma unroll
    for (int t = 0; t < 2; t++)
        #pragma unroll
        for (int r = 0; r < 4; r++) {
            const int c1 = 16 * (wv & 3) + 4 * lq + r;
            const int c2 = 32 * (wv >> 2) + 16 * t + l15;
            atomicAdd(GPmy + c1 * 64 + c2, acc[t][r]);
        }
    if (wv >= 4) {
        #pragma unroll
        for (int mm = 1; mm < 64; mm <<= 1) vsum += __shfl_xor(vsum, mm);
        if (lane == 0) atomicAdd(scal + 0, vsum + vsum);   // m = 2*sum(directed v)
    }
}

// ---------------- merge deg8 -> deg_row, GP8 -> GP (symmetrize M + M^T)
__global__ __launch_bounds__(256) void k_mrg(const float* __restrict__ deg8,
    const float* __restrict__ GP8, const int n, float* __restrict__ deg_row,
    float* __restrict__ GP) {
    const int bid = blockIdx.x;
    const int t = threadIdx.x;
    if (bid < 256) {
        const int i = bid * 256 + t;
        float s = 0.f;
        #pragma unroll
        for (int c = 0; c < 8; c++) s += deg8[(size_t)c * n + i];
        deg_row[i] = s;
    } else {
        const int j = (bid - 256) * 256 + t;
        const int jt = (j & 63) * 64 + (j >> 6);
        float s = 0.f;
        #pragma unroll
        for (int c = 0; c < 8; c++) s += GP8[(size_t)c * 4096 + j] + GP8[(size_t)c * 4096 + jt];
        GP[j] = s;
    }
}

// ---------------- k2m: G = S^T F via MFMA
__global__ __launch_bounds__(256) void k2m(const float* __restrict__ F,
    const u16* __restrict__ Sbf, float* __restrict__ G) {
    __shared__ uint32_t Ss[64 * 32];
    __shared__ uint32_t Fs[128 * 32];
    const int tid = threadIdx.x;
    const int lane = tid & 63;
    const int wv = __builtin_amdgcn_readfirstlane(tid >> 6);
    const int l15 = lane & 15, lq = lane >> 4;
    const int d0 = (blockIdx.x & 3) * 128;
    const int kblk = blockIdx.x >> 2;

    f32x4 acc[8];
    #pragma unroll
    for (int t8 = 0; t8 < 8; t8++)
        #pragma unroll
        for (int r = 0; r < 4; r++) acc[t8][r] = 0.f;

    const int s_ip = tid >> 3;
    const int s_cs = (tid & 7) * 8;
    const int f_dg = tid & 31;
    const int f_ipb = tid >> 5;

    for (int ch = 0; ch < 8; ch++) {
        const int i0 = kblk * 512 + ch * 64;
        {
            const u16x8 r0 = *(const u16x8*)&Sbf[(size_t)(i0 + 2 * s_ip) * 64 + s_cs];
            const u16x8 r1 = *(const u16x8*)&Sbf[(size_t)(i0 + 2 * s_ip + 1) * 64 + s_cs];
            #pragma unroll
            for (int j = 0; j < 8; j++) {
                const int c = s_cs + j;
                const uint32_t pk = (uint32_t)(u16)r0[j] | ((uint32_t)(u16)r1[j] << 16);
                Ss[c * 32 + (s_ip ^ (((c >> 2) & 7) << 2))] = pk;
            }
        }
        #pragma unroll
        for (int s = 0; s < 4; s++) {
            const int ip = f_ipb + 8 * s;
            const float4 a = *(const float4*)(F + (size_t)(i0 + 2 * ip) * 512 + d0 + 4 * f_dg);
            const float4 b = *(const float4*)(F + (size_t)(i0 + 2 * ip + 1) * 512 + d0 + 4 * f_dg);
            const float al[4] = {a.x, a.y, a.z, a.w};
            const float bl[4] = {b.x, b.y, b.z, b.w};
            #pragma unroll
            for (int j = 0; j < 4; j++) {
                const int d = 4 * f_dg + j;
                const uint32_t pk = (uint32_t)f2bf(al[j]) | ((uint32_t)f2bf(bl[j]) << 16);
                Fs[d * 32 + (ip ^ (((d >> 2) & 7) << 2))] = pk;
            }
        }
        __syncthreads();
        #pragma unroll
        for (int kk = 0; kk < 64; kk += 32) {
            const int w0 = (kk >> 1) + (lq << 2);
            const int ca = 16 * wv + l15;
            const bf16x8 afrag = *(const bf16x8*)&Ss[ca * 32 + (w0 ^ (((ca >> 2) & 7) << 2))];
            #pragma unroll
            for (int t8 = 0; t8 < 8; t8++) {
                const int d = 16 * t8 + l15;
                const bf16x8 bfrag = *(const bf16x8*)&Fs[d * 32 + (w0 ^ (((d >> 2) & 7) << 2))];
                acc[t8] = __builtin_amdgcn_mfma_f32_16x16x32_bf16(afrag, bfrag, acc[t8], 0, 0, 0);
            }
        }
        __syncthreads();
    }
    #pragma unroll
    for (int t8 = 0; t8 < 8; t8++) {
        #pragma unroll
        for (int r = 0; r < 4; r++) {
            const int c = 16 * wv + 4 * lq + r;
            const int d = d0 + 16 * t8 + l15;
            atomicAdd(G + (size_t)c * 512 + d, acc[t8][r]);
        }
    }
}

// ---------------- fused k x k reductions: SS=S^T S, SDS=(deg.S)^T S, u=S^T deg
__global__ __launch_bounds__(256) void k_kk(const u16* __restrict__ Sbf,
    const float* __restrict__ deg_row, float* __restrict__ SS,
    float* __restrict__ SDS, float* __restrict__ u_vec) {
    __shared__ float Pss[4][16][64];
    __shared__ float Psds[4][16][64];
    __shared__ float Pu[4][64];
    const int tid = threadIdx.x, lane = tid & 63;
    const int wv = __builtin_amdgcn_readfirstlane(tid >> 6);
    const int cs = blockIdx.x & 3, c0 = cs * 16;
    const int rbase = (blockIdx.x >> 2) * 512 + wv * 128;
    float ss[16], sds[16], ua = 0.f;
    #pragma unroll
    for (int cc = 0; cc < 16; cc++) { ss[cc] = 0.f; sds[cc] = 0.f; }
    for (int r = 0; r < 128; r++) {
        const int i = rbase + r;
        const float sv = bf2f(Sbf[(size_t)i * 64 + lane]);
        const float dr = deg_row[i];
        ua = fmaf(dr, sv, ua);
        const u16* srow = Sbf + (size_t)i * 64 + c0;
        #pragma unroll
        for (int cc = 0; cc < 16; cc++) {
            const float sc = bf2f(srow[cc]);
            ss[cc] = fmaf(sc, sv, ss[cc]);
            sds[cc] = fmaf(sc * dr, sv, sds[cc]);
        }
    }
    #pragma unroll
    for (int cc = 0; cc < 16; cc++) {
        Pss[wv][cc][lane] = ss[cc]; Psds[wv][cc][lane] = sds[cc];
    }
    Pu[wv][lane] = ua;
    __syncthreads();
    for (int q = 0; q < 4; q++) {
        const int cell = tid * 4 + q, cc = cell >> 6, l = cell & 63;
        atomicAdd(SS + (c0 + cc) * 64 + l, Pss[0][cc][l] + Pss[1][cc][l] + Pss[2][cc][l] + Pss[3][cc][l]);
        atomicAdd(SDS + (c0 + cc) * 64 + l, Psds[0][cc][l] + Psds[1][cc][l] + Psds[2][cc][l] + Psds[3][cc][l]);
    }
    if (cs == 0 && tid < 64)
        atomicAdd(u_vec + tid, Pu[0][tid] + Pu[1][tid] + Pu[2][tid] + Pu[3][tid]);
}

__device__ __forceinline__ float bred256(float v, float* red) {
    #pragma unroll
    for (int mm = 1; mm < 64; mm <<= 1) v += __shfl_xor(v, mm);
    const int t = threadIdx.x;
    __syncthreads();
    if ((t & 63) == 0) red[t >> 6] = v;
    __syncthreads();
    return red[0] + red[1] + red[2] + red[3];
}

// ---------------- FP = selu(G/sizes) + <G,FP>
__global__ __launch_bounds__(256) void k_fp(const float* __restrict__ G,
    const float* __restrict__ sizes, float* __restrict__ FP, float* __restrict__ scal) {
    __shared__ float red[4];
    const int idx = blockIdx.x * 256 + threadIdx.x;
    const int c = idx >> 9;
    const float g = G[idx];
    const float x = g / sizes[c];
    const float fp = 1.0507009873554805f * (x > 0.f ? x : 1.6732632423543772f * (__expf(x) - 1.f));
    FP[idx] = fp;
    const float gd = bred256(g * fp, red);
    if (threadIdx.x == 0) atomicAdd(scal + 2, gd);
}

// ---------------- FFt = FP FP^T
__global__ __launch_bounds__(256) void k_fft(const float* __restrict__ FP, float* __restrict__ FFt) {
    __shared__ float red[256];
    const int c = blockIdx.x;
    const int cp = threadIdx.x & 63, part = threadIdx.x >> 6;
    float a = 0.f;
    const int dbase = part * 128;
    for (int dd = 0; dd < 128; dd++)
        a = fmaf(FP[c * 512 + dbase + dd], FP[cp * 512 + dbase + dd], a);
    red[threadIdx.x] = a;
    __syncthreads();
    if (threadIdx.x < 64)
        FFt[c * 64 + threadIdx.x] = red[threadIdx.x] + red[threadIdx.x + 64] +
                                    red[threadIdx.x + 128] + red[threadIdx.x + 192];
}

// ---------------- logabsdet(StLS + 1) via LU
__global__ __launch_bounds__(64) void k_lu(const float* __restrict__ SDS,
    const float* __restrict__ GP, float* __restrict__ scal) {
    __shared__ float M[64][65];
    const int l = threadIdx.x;
    for (int c = 0; c < 64; c++) M[l][c] = SDS[l * 64 + c] - GP[l * 64 + c] + 1.0f;
    __syncthreads();
    float logdet = 0.f;
    for (int k = 0; k < 64; k++) {
        float v = (l >= k) ? fabsf(M[l][k]) : -1.f;
        int idx = l;
        #pragma unroll
        for (int mm = 1; mm < 64; mm <<= 1) {
            const float ov = __shfl_xor(v, mm);
            const int oi = __shfl_xor(idx, mm);
            if (ov > v || (ov == v && oi < idx)) { v = ov; idx = oi; }
        }
        if (idx != k) {
            const float t1 = M[k][l], t2 = M[idx][l];
            __syncthreads();
            M[k][l] = t2;
            M[idx][l] = t1;
        }
        __syncthreads();
        const float piv = M[k][k];
        logdet += logf(fabsf(piv));
        if (l > k) {
            const float f = M[l][k] / piv;
            for (int c = k + 1; c < 64; c++) M[l][c] = fmaf(-f, M[k][c], M[l][c]);
        }
        __syncthreads();
    }
    if (l == 0) scal[3] = logdet;
}

// ---------------- final loss assembly
__global__ __launch_bounds__(256) void k_final(const float* __restrict__ GP,
    const float* __restrict__ SS, const float* __restrict__ FFt, const float* __restrict__ u_vec,
    const float* __restrict__ sizes, const float* __restrict__ deg_row,
    const float* __restrict__ AS64, const float* __restrict__ S,
    const float* __restrict__ scal, float* __restrict__ out_loss, const float fn) {
    __shared__ float red[4];
    const int t = threadIdx.x;
    float sA = 0.f, trl = 0.f, trg = 0.f, u2 = 0.f, sz2 = 0.f;
    for (int q = t; q < 4096; q += 256) sA += SS[q] * FFt[q];
    for (int q = t; q < 4096; q += 256) {
        const int i = q >> 6, c = q & 63;
        const float ls = deg_row[i] * S[i * 64 + c] - AS64[q];
        trl += ls * FFt[c * 64 + i];
    }
    if (t < 64) { trg = GP[t * 65]; u2 = u_vec[t] * u_vec[t]; sz2 = sizes[t] * sizes[t]; }
    sA = bred256(sA, red);
    trl = bred256(trl, red);
    trg = bred256(trg, red);
    u2 = bred256(u2, red);
    sz2 = bred256(sz2, red);
    if (t == 0) {
        const float m = scal[0], sumF2 = scal[1], gfp = scal[2], lad = scal[3];
        const float spectral = -(trg - u2 / (2.f * m)) / (2.f * m);
        const float collapse = sqrtf(sz2) / fn * 8.f - 1.f;
        const float frob = sqrtf(fmaxf(sA - 2.f * gfp + sumF2, 0.f)) * 1e-4f;
        const float one_two = sqrtf(sz2) * 1e-4f;
        const float smooth = lad * (-1e-4f);
        out_loss[0] = spectral + 0.1f * collapse + smooth + trl + frob + one_two;
    }
}

extern "C" void kernel_launch(void* const* d_in, const int* in_sizes, int n_in,
                              void* d_out, int out_size, void* d_ws, size_t ws_size,
                              hipStream_t stream) {
    const float* F = (const float*)d_in[0];
    const int* esrc = (const int*)d_in[1];
    const int* edst = (const int*)d_in[2];
    const float* ev = (const float*)d_in[3];
    const float* Wg = (const float*)d_in[4];
    const float* bg = (const float*)d_in[5];
    const int n = in_sizes[0] / 512;
    const int E = in_sizes[1];
    const int E2 = E >> 1;   // directed half (list is symmetrized concat)

    float* outF = (float*)d_out;                 // FP [64*512]
    float* outS = outF + 64 * 512;               // S [n*64]
    float* outL = outS + (size_t)n * 64;         // loss scalar

    char* w = (char*)d_ws;
    // ---- zeroed region
    float* sizes = (float*)w;                    // 64
    float* u_vec = sizes + 64;                   // 64
    float* scal = u_vec + 64;                    // 64 (m, sumF2, gfp, logabsdet)
    float* G = scal + 64;                        // 64*512
    float* GP = G + 64 * 512;                    // 4096
    float* SS = GP + 4096;                       // 4096
    float* SDS = SS + 4096;                      // 4096
    float* AS64 = SDS + 4096;                    // 4096
    float* GP8 = AS64 + 4096;                    // 8*4096
    float* deg8 = GP8 + 8 * 4096;                // 8n
    char* zend = (char*)(deg8 + (size_t)8 * n);
    const size_t zero_bytes = (size_t)(zend - w);
    // ---- non-zeroed region
    float* deg_row = (float*)zend;               // n
    float* FFt = deg_row + n;                    // 4096
    u16* Sbf = (u16*)(FFt + 4096);               // n*64
    u16* Wt = Sbf + (size_t)n * 64;              // 64*512

    hipMemsetAsync(d_ws, 0, zero_bytes, stream);
    k_prep<<<128, 256, 0, stream>>>(Wg, Wt);
    k1<<<n / 64, 256, 0, stream>>>(F, Wt, bg, outS, Sbf, sizes, scal);
    k_sweep<<<1024, 512, 0, stream>>>(esrc, edst, ev, Sbf, outS, E2, GP8, deg8, n, AS64, scal);
    k2m<<<512, 256, 0, stream>>>(F, Sbf, G);
    k_mrg<<<272, 256, 0, stream>>>(deg8, GP8, n, deg_row, GP);
    k_kk<<<(n / 512) * 4, 256, 0, stream>>>(Sbf, deg_row, SS, SDS, u_vec);
    k_fp<<<128, 256, 0, stream>>>(G, sizes, outF, scal);
    k_fft<<<64, 256, 0, stream>>>(outF, FFt);
    k_lu<<<1, 64, 0, stream>>>(SDS, GP, scal);
    k_final<<<1, 256, 0, stream>>>(GP, SS, FFt, u_vec, sizes, deg_row, AS64, outS, scal, outL, (float)n);
}

// Round 9
// 530.102 us; speedup vs baseline: 2.7982x; 1.0281x over previous
//
#include <hip/hip_runtime.h>
#include <hip/hip_bf16.h>
#include <cstdint>
#include <cstddef>

typedef unsigned short u16;
typedef float f32x4 __attribute__((ext_vector_type(4)));
typedef short bf16x8 __attribute__((ext_vector_type(8)));
typedef unsigned short u16x8 __attribute__((ext_vector_type(8)));

__device__ __forceinline__ u16 f2bf(float f) {
    uint32_t u = __float_as_uint(f);
    u += 0x7fffu + ((u >> 16) & 1u);
    return (u16)(u >> 16);
}
__device__ __forceinline__ float bf2f(u16 h) {
    return __uint_as_float(((uint32_t)h) << 16);
}

// conflict-free word swizzle for [64 rows][32 words] pair-packed tiles
#define SWZ(c) ((((c) ^ ((c) >> 3)) & 7) << 2)

// ---------------- W pre-transpose + swizzle
__global__ __launch_bounds__(256) void k_prep(const float* __restrict__ Wg, u16* __restrict__ Wt) {
    int idx = blockIdx.x * 256 + threadIdx.x;   // 32768
    int k = idx >> 6, c = idx & 63;
    int lin = c * 512 + (k ^ ((c & 7) << 3));
    Wt[lin] = f2bf(Wg[idx]);
}

// ---------------- fused logits GEMM + softmax
__global__ __launch_bounds__(256) void k1(const float* __restrict__ F,
    const u16* __restrict__ WtG, const float* __restrict__ bias,
    float* __restrict__ S_out, u16* __restrict__ Sbf,
    float* __restrict__ sizes, float* __restrict__ scal) {
    __shared__ __align__(16) u16 Wl[64 * 512];
    __shared__ __align__(16) u16 Al[64 * 64];
    __shared__ float red4[4];
    const int tid = threadIdx.x;
    const int row0 = blockIdx.x * 64;
    for (int j = tid; j < 4096; j += 256)
        ((uint4*)Wl)[j] = ((const uint4*)WtG)[j];

    const int lane = tid & 63;
    const int wv = __builtin_amdgcn_readfirstlane(tid >> 6);
    const int l15 = lane & 15, lq = lane >> 4;
    f32x4 acc[4];
    #pragma unroll
    for (int tn = 0; tn < 4; tn++)
        #pragma unroll
        for (int e = 0; e < 4; e++) acc[tn][e] = 0.f;
    float sumf2 = 0.f;
    const int sr = tid >> 2, skq = tid & 3;
    const int sw = (sr & 7) << 3;

    for (int k0 = 0; k0 < 512; k0 += 64) {
        const float* fp = F + (size_t)(row0 + sr) * 512 + k0 + skq * 16;
        float4 v[4];
        u16 h[16];
        #pragma unroll
        for (int q = 0; q < 4; q++) v[q] = ((const float4*)fp)[q];
        #pragma unroll
        for (int q = 0; q < 4; q++) {
            sumf2 += v[q].x * v[q].x + v[q].y * v[q].y + v[q].z * v[q].z + v[q].w * v[q].w;
            h[q * 4 + 0] = f2bf(v[q].x); h[q * 4 + 1] = f2bf(v[q].y);
            h[q * 4 + 2] = f2bf(v[q].z); h[q * 4 + 3] = f2bf(v[q].w);
        }
        #pragma unroll
        for (int half = 0; half < 2; half++) {
            u16x8 pk;
            #pragma unroll
            for (int e2 = 0; e2 < 8; e2++) pk[e2] = h[half * 8 + e2];
            *(u16x8*)&Al[sr * 64 + ((skq * 16 + half * 8) ^ sw)] = pk;
        }
        __syncthreads();
        #pragma unroll
        for (int kk = 0; kk < 64; kk += 32) {
            const int arow = wv * 16 + l15;
            bf16x8 a = *(const bf16x8*)&Al[arow * 64 + ((kk + lq * 8) ^ ((arow & 7) << 3))];
            #pragma unroll
            for (int tn = 0; tn < 4; tn++) {
                const int bc = tn * 16 + l15;
                bf16x8 b = *(const bf16x8*)&Wl[bc * 512 + ((k0 + kk + lq * 8) ^ ((bc & 7) << 3))];
                acc[tn] = __builtin_amdgcn_mfma_f32_16x16x32_bf16(a, b, acc[tn], 0, 0, 0);
            }
        }
        __syncthreads();
    }

    float bias4[4], szacc[4] = {0.f, 0.f, 0.f, 0.f};
    #pragma unroll
    for (int tn = 0; tn < 4; tn++) bias4[tn] = bias[tn * 16 + l15];
    #pragma unroll
    for (int r2 = 0; r2 < 4; r2++) {
        float L[4];
        #pragma unroll
        for (int tn = 0; tn < 4; tn++) L[tn] = acc[tn][r2] + bias4[tn];
        float mx = fmaxf(fmaxf(L[0], L[1]), fmaxf(L[2], L[3]));
        #pragma unroll
        for (int mm = 1; mm < 16; mm <<= 1) mx = fmaxf(mx, __shfl_xor(mx, mm));
        float e[4], s = 0.f;
        #pragma unroll
        for (int tn = 0; tn < 4; tn++) { e[tn] = __expf(L[tn] - mx); s += e[tn]; }
        #pragma unroll
        for (int mm = 1; mm < 16; mm <<= 1) s += __shfl_xor(s, mm);
        const float inv = 1.f / s;
        const size_t grow = (size_t)(row0 + wv * 16 + lq * 4 + r2);
        #pragma unroll
        for (int tn = 0; tn < 4; tn++) {
            const float svl = e[tn] * inv;
            S_out[grow * 64 + tn * 16 + l15] = svl;
            Sbf[grow * 64 + tn * 16 + l15] = f2bf(svl);
            szacc[tn] += svl;
        }
    }
    #pragma unroll
    for (int tn = 0; tn < 4; tn++) {
        float vs = szacc[tn];
        vs += __shfl_xor(vs, 16);
        vs += __shfl_xor(vs, 32);
        if (lq == 0) atomicAdd(sizes + tn * 16 + l15, vs);
    }
    #pragma unroll
    for (int mm = 1; mm < 64; mm <<= 1) sumf2 += __shfl_xor(sumf2, mm);
    if (lane == 0) red4[wv] = sumf2;
    __syncthreads();
    if (tid == 0) atomicAdd(scal + 1, red4[0] + red4[1] + red4[2] + red4[3]);
}

// ---------------- k_sweep: one pass over the DIRECTED half of the edge list.
// Stages 4 tiles: T = S[t], P = v⊙S[t] (isP threads); Q = S[s], R = v⊙S[s] (!isP).
// MFMA: M += P^T Q (→GP = M+M^T), SDS += R^T Q + P^T T.
// Also: u += v(S[s]+S[t]) (VALU regs), m, deg64/AS64 rare branches.
__global__ __launch_bounds__(512) void k_sweep(const int* __restrict__ esrc,
    const int* __restrict__ edst, const float* __restrict__ ev,
    const u16* __restrict__ Sbf, const float* __restrict__ S, const int E2,
    float* __restrict__ GP8, float* __restrict__ SDS8, float* __restrict__ u8,
    float* __restrict__ AS64, float* __restrict__ deg64, float* __restrict__ scal) {
    __shared__ uint32_t Tl[2][2048];
    __shared__ uint32_t Pl[2][2048];
    __shared__ uint32_t Ql[2][2048];
    __shared__ uint32_t Rl[2][2048];
    const int tid = threadIdx.x;
    const int lane = tid & 63;
    const int wv = __builtin_amdgcn_readfirstlane(tid >> 6);
    const int l15 = lane & 15, lq = lane >> 4;
    const int xcd = blockIdx.x & 7;
    float* __restrict__ GPmy = GP8 + (size_t)xcd * 4096;
    float* __restrict__ SDSmy = SDS8 + (size_t)xcd * 4096;
    float* __restrict__ umy = u8 + (size_t)xcd * 64;

    const bool isP = tid < 256;
    const int st = tid & 255;
    const int p = st >> 3, g = st & 7;
    float vsum = 0.f;
    float uacc[8];
    #pragma unroll
    for (int j = 0; j < 8; j++) uacc[j] = 0.f;

    f32x4 aG[2], aS[2];
    #pragma unroll
    for (int t = 0; t < 2; t++)
        #pragma unroll
        for (int r = 0; r < 4; r++) { aG[t][r] = 0.f; aS[t][r] = 0.f; }

    const int ma = 16 * (wv & 3) + l15;
    const int aoff = ma * 32, aswz = SWZ(ma);
    const int nb0 = 32 * (wv >> 2) + l15;
    const int nb1 = nb0 + 16;
    const int b0off = nb0 * 32, b0swz = SWZ(nb0);
    const int b1off = nb1 * 32, b1swz = SWZ(nb1);

    const int nch = E2 >> 6;
    const int stride = gridDim.x;
    int ch = blockIdx.x;
    if (ch >= nch) return;

    int2 ia_c, ib_c;
    float2 vv_c;
    {
        const int e0 = (ch << 6) + 2 * p;
        ia_c = isP ? *(const int2*)&edst[e0] : *(const int2*)&esrc[e0];
        ib_c = isP ? *(const int2*)&esrc[e0] : *(const int2*)&edst[e0];
        vv_c = *(const float2*)&ev[e0];
    }
    u16x8 ra_c = *(const u16x8*)&Sbf[(size_t)ia_c.x * 64 + 8 * g];
    u16x8 rb_c = *(const u16x8*)&Sbf[(size_t)ia_c.y * 64 + 8 * g];

    int buf = 0;
    while (true) {
        // ---- stage tiles (raw + v-scaled), proven VALU path
        if (isP) {
            #pragma unroll
            for (int j = 0; j < 8; j++) {
                const int c = 8 * g + j;
                const int off = c * 32 + (p ^ SWZ(c));
                Tl[buf][off] = (uint32_t)(u16)ra_c[j] | ((uint32_t)(u16)rb_c[j] << 16);
                Pl[buf][off] = (uint32_t)f2bf(vv_c.x * bf2f((u16)ra_c[j])) |
                               ((uint32_t)f2bf(vv_c.y * bf2f((u16)rb_c[j])) << 16);
            }
        } else {
            #pragma unroll
            for (int j = 0; j < 8; j++) {
                const int c = 8 * g + j;
                const int off = c * 32 + (p ^ SWZ(c));
                Ql[buf][off] = (uint32_t)(u16)ra_c[j] | ((uint32_t)(u16)rb_c[j] << 16);
                Rl[buf][off] = (uint32_t)f2bf(vv_c.x * bf2f((u16)ra_c[j])) |
                               ((uint32_t)f2bf(vv_c.y * bf2f((u16)rb_c[j])) << 16);
            }
        }
        // ---- u accumulation (f32 regs)
        #pragma unroll
        for (int j = 0; j < 8; j++)
            uacc[j] = fmaf(vv_c.x, bf2f((u16)ra_c[j]),
                      fmaf(vv_c.y, bf2f((u16)rb_c[j]), uacc[j]));
        if (!isP && g == 0) vsum += vv_c.x + vv_c.y;
        // ---- rare first-64 paths: deg64 + AS64 (f32 exact)
        if (g == 0) {
            if (ib_c.x < 64) atomicAdd(deg64 + ib_c.x, vv_c.x);
            if (ib_c.y < 64) atomicAdd(deg64 + ib_c.y, vv_c.y);
        }
        if (ib_c.x < 64) {
            const float4 fa = *(const float4*)(S + (size_t)ia_c.x * 64 + 8 * g);
            const float4 fb = *(const float4*)(S + (size_t)ia_c.x * 64 + 8 * g + 4);
            float* dst = AS64 + ib_c.x * 64 + 8 * g;
            atomicAdd(dst + 0, vv_c.x * fa.x); atomicAdd(dst + 1, vv_c.x * fa.y);
            atomicAdd(dst + 2, vv_c.x * fa.z); atomicAdd(dst + 3, vv_c.x * fa.w);
            atomicAdd(dst + 4, vv_c.x * fb.x); atomicAdd(dst + 5, vv_c.x * fb.y);
            atomicAdd(dst + 6, vv_c.x * fb.z); atomicAdd(dst + 7, vv_c.x * fb.w);
        }
        if (ib_c.y < 64) {
            const float4 fa = *(const float4*)(S + (size_t)ia_c.y * 64 + 8 * g);
            const float4 fb = *(const float4*)(S + (size_t)ia_c.y * 64 + 8 * g + 4);
            float* dst = AS64 + ib_c.y * 64 + 8 * g;
            atomicAdd(dst + 0, vv_c.y * fa.x); atomicAdd(dst + 1, vv_c.y * fa.y);
            atomicAdd(dst + 2, vv_c.y * fa.z); atomicAdd(dst + 3, vv_c.y * fa.w);
            atomicAdd(dst + 4, vv_c.y * fb.x); atomicAdd(dst + 5, vv_c.y * fb.y);
            atomicAdd(dst + 6, vv_c.y * fb.z); atomicAdd(dst + 7, vv_c.y * fb.w);
        }
        // ---- issue next chunk's loads
        const int chn = ch + stride;
        const int chc = chn < nch ? chn : (nch - 1);
        int2 ia_n, ib_n;
        float2 vv_n;
        {
            const int e0 = (chc << 6) + 2 * p;
            ia_n = isP ? *(const int2*)&edst[e0] : *(const int2*)&esrc[e0];
            ib_n = isP ? *(const int2*)&esrc[e0] : *(const int2*)&edst[e0];
            vv_n = *(const float2*)&ev[e0];
        }
        const u16x8 ra_n = *(const u16x8*)&Sbf[(size_t)ia_n.x * 64 + 8 * g];
        const u16x8 rb_n = *(const u16x8*)&Sbf[(size_t)ia_n.y * 64 + 8 * g];
        __syncthreads();
        // ---- MFMA phase (all fragments from LDS, proven pattern)
        #pragma unroll
        for (int half = 0; half < 2; half++) {
            const int w0 = half * 16 + lq * 4;
            const bf16x8 afP = *(const bf16x8*)&Pl[buf][aoff + (w0 ^ aswz)];
            const bf16x8 afR = *(const bf16x8*)&Rl[buf][aoff + (w0 ^ aswz)];
            const bf16x8 qb0 = *(const bf16x8*)&Ql[buf][b0off + (w0 ^ b0swz)];
            const bf16x8 qb1 = *(const bf16x8*)&Ql[buf][b1off + (w0 ^ b1swz)];
            const bf16x8 tb0 = *(const bf16x8*)&Tl[buf][b0off + (w0 ^ b0swz)];
            const bf16x8 tb1 = *(const bf16x8*)&Tl[buf][b1off + (w0 ^ b1swz)];
            aG[0] = __builtin_amdgcn_mfma_f32_16x16x32_bf16(afP, qb0, aG[0], 0, 0, 0);
            aG[1] = __builtin_amdgcn_mfma_f32_16x16x32_bf16(afP, qb1, aG[1], 0, 0, 0);
            aS[0] = __builtin_amdgcn_mfma_f32_16x16x32_bf16(afR, qb0, aS[0], 0, 0, 0);
            aS[1] = __builtin_amdgcn_mfma_f32_16x16x32_bf16(afR, qb1, aS[1], 0, 0, 0);
            aS[0] = __builtin_amdgcn_mfma_f32_16x16x32_bf16(afP, tb0, aS[0], 0, 0, 0);
            aS[1] = __builtin_amdgcn_mfma_f32_16x16x32_bf16(afP, tb1, aS[1], 0, 0, 0);
        }
        ch = chn;
        if (ch >= nch) break;
        ia_c = ia_n; ib_c = ib_n; vv_c = vv_n; ra_c = ra_n; rb_c = rb_n;
        buf ^= 1;
    }
    // ---- epilogue: M / SDS partials (XCD-private)
    #pragma unroll
    for (int t = 0; t < 2; t++)
        #pragma unroll
        for (int r = 0; r < 4; r++) {
            const int c1 = 16 * (wv & 3) + 4 * lq + r;
            const int c2 = 32 * (wv >> 2) + 16 * t + l15;
            atomicAdd(GPmy + c1 * 64 + c2, aG[t][r]);
            atomicAdd(SDSmy + c1 * 64 + c2, aS[t][r]);
        }
    // ---- u: reduce over p-bits within wave (lane bits 3..5), lanes 0..7 emit
    #pragma unroll
    for (int j = 0; j < 8; j++) {
        uacc[j] += __shfl_xor(uacc[j], 8);
        uacc[j] += __shfl_xor(uacc[j], 16);
        uacc[j] += __shfl_xor(uacc[j], 32);
    }
    if (lane < 8) {
        #pragma unroll
        for (int j = 0; j < 8; j++)
            atomicAdd(umy + 8 * lane + j, uacc[j]);
    }
    if (wv >= 4) {
        #pragma unroll
        for (int mm = 1; mm < 64; mm <<= 1) vsum += __shfl_xor(vsum, mm);
        if (lane == 0) atomicAdd(scal + 0, vsum + vsum);   // m = 2*sum(directed v)
    }
}

// ---------------- merge: GP = sym(M8), SDS = sum(SDS8), u_vec = sum(u8)
__global__ __launch_bounds__(256) void k_mrg(const float* __restrict__ GP8,
    const float* __restrict__ SDS8, const float* __restrict__ u8,
    float* __restrict__ GP, float* __restrict__ SDS, float* __restrict__ u_vec) {
    const int bid = blockIdx.x;
    const int t = threadIdx.x;
    if (bid < 16) {
        const int j = bid * 256 + t;
        const int jt = (j & 63) * 64 + (j >> 6);
        float s = 0.f;
        #pragma unroll
        for (int c = 0; c < 8; c++)
            s += GP8[(size_t)c * 4096 + j] + GP8[(size_t)c * 4096 + jt];
        GP[j] = s;
    } else if (bid < 32) {
        const int j = (bid - 16) * 256 + t;
        float s = 0.f;
        #pragma unroll
        for (int c = 0; c < 8; c++) s += SDS8[(size_t)c * 4096 + j];
        SDS[j] = s;
    } else if (t < 64) {
        float s = 0.f;
        #pragma unroll
        for (int c = 0; c < 8; c++) s += u8[c * 64 + t];
        u_vec[t] = s;
    }
}

// ---------------- k2m: G = S^T F via MFMA
__global__ __launch_bounds__(256) void k2m(const float* __restrict__ F,
    const u16* __restrict__ Sbf, float* __restrict__ G) {
    __shared__ uint32_t Ss[64 * 32];
    __shared__ uint32_t Fs[128 * 32];
    const int tid = threadIdx.x;
    const int lane = tid & 63;
    const int wv = __builtin_amdgcn_readfirstlane(tid >> 6);
    const int l15 = lane & 15, lq = lane >> 4;
    const int d0 = (blockIdx.x & 3) * 128;
    const int kblk = blockIdx.x >> 2;

    f32x4 acc[8];
    #pragma unroll
    for (int t8 = 0; t8 < 8; t8++)
        #pragma unroll
        for (int r = 0; r < 4; r++) acc[t8][r] = 0.f;

    const int s_ip = tid >> 3;
    const int s_cs = (tid & 7) * 8;
    const int f_dg = tid & 31;
    const int f_ipb = tid >> 5;

    for (int ch = 0; ch < 8; ch++) {
        const int i0 = kblk * 512 + ch * 64;
        {
            const u16x8 r0 = *(const u16x8*)&Sbf[(size_t)(i0 + 2 * s_ip) * 64 + s_cs];
            const u16x8 r1 = *(const u16x8*)&Sbf[(size_t)(i0 + 2 * s_ip + 1) * 64 + s_cs];
            #pragma unroll
            for (int j = 0; j < 8; j++) {
                const int c = s_cs + j;
                const uint32_t pk = (uint32_t)(u16)r0[j] | ((uint32_t)(u16)r1[j] << 16);
                Ss[c * 32 + (s_ip ^ (((c >> 2) & 7) << 2))] = pk;
            }
        }
        #pragma unroll
        for (int s = 0; s < 4; s++) {
            const int ip = f_ipb + 8 * s;
            const float4 a = *(const float4*)(F + (size_t)(i0 + 2 * ip) * 512 + d0 + 4 * f_dg);
            const float4 b = *(const float4*)(F + (size_t)(i0 + 2 * ip + 1) * 512 + d0 + 4 * f_dg);
            const float al[4] = {a.x, a.y, a.z, a.w};
            const float bl[4] = {b.x, b.y, b.z, b.w};
            #pragma unroll
            for (int j = 0; j < 4; j++) {
                const int d = 4 * f_dg + j;
                const uint32_t pk = (uint32_t)f2bf(al[j]) | ((uint32_t)f2bf(bl[j]) << 16);
                Fs[d * 32 + (ip ^ (((d >> 2) & 7) << 2))] = pk;
            }
        }
        __syncthreads();
        #pragma unroll
        for (int kk = 0; kk < 64; kk += 32) {
            const int w0 = (kk >> 1) + (lq << 2);
            const int ca = 16 * wv + l15;
            const bf16x8 afrag = *(const bf16x8*)&Ss[ca * 32 + (w0 ^ (((ca >> 2) & 7) << 2))];
            #pragma unroll
            for (int t8 = 0; t8 < 8; t8++) {
                const int d = 16 * t8 + l15;
                const bf16x8 bfrag = *(const bf16x8*)&Fs[d * 32 + (w0 ^ (((d >> 2) & 7) << 2))];
                acc[t8] = __builtin_amdgcn_mfma_f32_16x16x32_bf16(afrag, bfrag, acc[t8], 0, 0, 0);
            }
        }
        __syncthreads();
    }
    #pragma unroll
    for (int t8 = 0; t8 < 8; t8++) {
        #pragma unroll
        for (int r = 0; r < 4; r++) {
            const int c = 16 * wv + 4 * lq + r;
            const int d = d0 + 16 * t8 + l15;
            atomicAdd(G + (size_t)c * 512 + d, acc[t8][r]);
        }
    }
}

// ---------------- SS = S^T S
__global__ __launch_bounds__(256) void k_kk(const u16* __restrict__ Sbf,
    float* __restrict__ SS) {
    __shared__ float Pss[4][16][64];
    const int tid = threadIdx.x, lane = tid & 63;
    const int wv = __builtin_amdgcn_readfirstlane(tid >> 6);
    const int cs = blockIdx.x & 3, c0 = cs * 16;
    const int rbase = (blockIdx.x >> 2) * 512 + wv * 128;
    float ss[16];
    #pragma unroll
    for (int cc = 0; cc < 16; cc++) ss[cc] = 0.f;
    for (int r = 0; r < 128; r++) {
        const int i = rbase + r;
        const float sv = bf2f(Sbf[(size_t)i * 64 + lane]);
        const u16* srow = Sbf + (size_t)i * 64 + c0;
        #pragma unroll
        for (int cc = 0; cc < 16; cc++)
            ss[cc] = fmaf(bf2f(srow[cc]), sv, ss[cc]);
    }
    #pragma unroll
    for (int cc = 0; cc < 16; cc++) Pss[wv][cc][lane] = ss[cc];
    __syncthreads();
    for (int q = 0; q < 4; q++) {
        const int cell = tid * 4 + q, cc = cell >> 6, l = cell & 63;
        atomicAdd(SS + (c0 + cc) * 64 + l,
                  Pss[0][cc][l] + Pss[1][cc][l] + Pss[2][cc][l] + Pss[3][cc][l]);
    }
}

__device__ __forceinline__ float bred256(float v, float* red) {
    #pragma unroll
    for (int mm = 1; mm < 64; mm <<= 1) v += __shfl_xor(v, mm);
    const int t = threadIdx.x;
    __syncthreads();
    if ((t & 63) == 0) red[t >> 6] = v;
    __syncthreads();
    return red[0] + red[1] + red[2] + red[3];
}

// ---------------- FP = selu(G/sizes) + <G,FP>
__global__ __launch_bounds__(256) void k_fp(const float* __restrict__ G,
    const float* __restrict__ sizes, float* __restrict__ FP, float* __restrict__ scal) {
    __shared__ float red[4];
    const int idx = blockIdx.x * 256 + threadIdx.x;
    const int c = idx >> 9;
    const float g = G[idx];
    const float x = g / sizes[c];
    const float fp = 1.0507009873554805f * (x > 0.f ? x : 1.6732632423543772f * (__expf(x) - 1.f));
    FP[idx] = fp;
    const float gd = bred256(g * fp, red);
    if (threadIdx.x == 0) atomicAdd(scal + 2, gd);
}

// ---------------- FFt = FP FP^T
__global__ __launch_bounds__(256) void k_fft(const float* __restrict__ FP, float* __restrict__ FFt) {
    __shared__ float red[256];
    const int c = blockIdx.x;
    const int cp = threadIdx.x & 63, part = threadIdx.x >> 6;
    float a = 0.f;
    const int dbase = part * 128;
    for (int dd = 0; dd < 128; dd++)
        a = fmaf(FP[c * 512 + dbase + dd], FP[cp * 512 + dbase + dd], a);
    red[threadIdx.x] = a;
    __syncthreads();
    if (threadIdx.x < 64)
        FFt[c * 64 + threadIdx.x] = red[threadIdx.x] + red[threadIdx.x + 64] +
                                    red[threadIdx.x + 128] + red[threadIdx.x + 192];
}

// ---------------- logabsdet(StLS + 1) via LU
__global__ __launch_bounds__(64) void k_lu(const float* __restrict__ SDS,
    const float* __restrict__ GP, float* __restrict__ scal) {
    __shared__ float M[64][65];
    const int l = threadIdx.x;
    for (int c = 0; c < 64; c++) M[l][c] = SDS[l * 64 + c] - GP[l * 64 + c] + 1.0f;
    __syncthreads();
    float logdet = 0.f;
    for (int k = 0; k < 64; k++) {
        float v = (l >= k) ? fabsf(M[l][k]) : -1.f;
        int idx = l;
        #pragma unroll
        for (int mm = 1; mm < 64; mm <<= 1) {
            const float ov = __shfl_xor(v, mm);
            const int oi = __shfl_xor(idx, mm);
            if (ov > v || (ov == v && oi < idx)) { v = ov; idx = oi; }
        }
        if (idx != k) {
            const float t1 = M[k][l], t2 = M[idx][l];
            __syncthreads();
            M[k][l] = t2;
            M[idx][l] = t1;
        }
        __syncthreads();
        const float piv = M[k][k];
        logdet += logf(fabsf(piv));
        if (l > k) {
            const float f = M[l][k] / piv;
            for (int c = k + 1; c < 64; c++) M[l][c] = fmaf(-f, M[k][c], M[l][c]);
        }
        __syncthreads();
    }
    if (l == 0) scal[3] = logdet;
}

// ---------------- final loss assembly
__global__ __launch_bounds__(256) void k_final(const float* __restrict__ GP,
    const float* __restrict__ SS, const float* __restrict__ FFt, const float* __restrict__ u_vec,
    const float* __restrict__ sizes, const float* __restrict__ deg64,
    const float* __restrict__ AS64, const float* __restrict__ S,
    const float* __restrict__ scal, float* __restrict__ out_loss, const float fn) {
    __shared__ float red[4];
    const int t = threadIdx.x;
    float sA = 0.f, trl = 0.f, trg = 0.f, u2 = 0.f, sz2 = 0.f;
    for (int q = t; q < 4096; q += 256) sA += SS[q] * FFt[q];
    for (int q = t; q < 4096; q += 256) {
        const int i = q >> 6, c = q & 63;
        const float ls = deg64[i] * S[i * 64 + c] - AS64[q];
        trl += ls * FFt[c * 64 + i];
    }
    if (t < 64) { trg = GP[t * 65]; u2 = u_vec[t] * u_vec[t]; sz2 = sizes[t] * sizes[t]; }
    sA = bred256(sA, red);
    trl = bred256(trl, red);
    trg = bred256(trg, red);
    u2 = bred256(u2, red);
    sz2 = bred256(sz2, red);
    if (t == 0) {
        const float m = scal[0], sumF2 = scal[1], gfp = scal[2], lad = scal[3];
        const float spectral = -(trg - u2 / (2.f * m)) / (2.f * m);
        const float collapse = sqrtf(sz2) / fn * 8.f - 1.f;
        const float frob = sqrtf(fmaxf(sA - 2.f * gfp + sumF2, 0.f)) * 1e-4f;
        const float one_two = sqrtf(sz2) * 1e-4f;
        const float smooth = lad * (-1e-4f);
        out_loss[0] = spectral + 0.1f * collapse + smooth + trl + frob + one_two;
    }
}

extern "C" void kernel_launch(void* const* d_in, const int* in_sizes, int n_in,
                              void* d_out, int out_size, void* d_ws, size_t ws_size,
                              hipStream_t stream) {
    const float* F = (const float*)d_in[0];
    const int* esrc = (const int*)d_in[1];
    const int* edst = (const int*)d_in[2];
    const float* ev = (const float*)d_in[3];
    const float* Wg = (const float*)d_in[4];
    const float* bg = (const float*)d_in[5];
    const int n = in_sizes[0] / 512;
    const int E = in_sizes[1];
    const int E2 = E >> 1;   // directed half (list is symmetrized concat)

    float* outF = (float*)d_out;                 // FP [64*512]
    float* outS = outF + 64 * 512;               // S [n*64]
    float* outL = outS + (size_t)n * 64;         // loss scalar

    char* w = (char*)d_ws;
    // ---- zeroed region
    float* sizes = (float*)w;                    // 64
    float* u_vec = sizes + 64;                   // 64
    float* scal = u_vec + 64;                    // 64 (m, sumF2, gfp, logabsdet)
    float* G = scal + 64;                        // 64*512
    float* SS = G + 64 * 512;                    // 4096
    float* AS64 = SS + 4096;                     // 4096
    float* deg64 = AS64 + 4096;                  // 64
    float* GP8 = deg64 + 64;                     // 8*4096
    float* SDS8 = GP8 + 8 * 4096;                // 8*4096
    float* u8 = SDS8 + 8 * 4096;                 // 8*64
    char* zend = (char*)(u8 + 512);
    const size_t zero_bytes = (size_t)(zend - w);
    // ---- non-zeroed region
    float* GP = (float*)zend;                    // 4096
    float* SDS = GP + 4096;                      // 4096
    float* FFt = SDS + 4096;                     // 4096
    u16* Sbf = (u16*)(FFt + 4096);               // n*64
    u16* Wt = Sbf + (size_t)n * 64;              // 64*512

    hipMemsetAsync(d_ws, 0, zero_bytes, stream);
    k_prep<<<128, 256, 0, stream>>>(Wg, Wt);
    k1<<<n / 64, 256, 0, stream>>>(F, Wt, bg, outS, Sbf, sizes, scal);
    k_sweep<<<512, 512, 0, stream>>>(esrc, edst, ev, Sbf, outS, E2, GP8, SDS8, u8, AS64, deg64, scal);
    k2m<<<512, 256, 0, stream>>>(F, Sbf, G);
    k_mrg<<<33, 256, 0, stream>>>(GP8, SDS8, u8, GP, SDS, u_vec);
    k_kk<<<(n / 512) * 4, 256, 0, stream>>>(Sbf, SS);
    k_fp<<<128, 256, 0, stream>>>(G, sizes, outF, scal);
    k_fft<<<64, 256, 0, stream>>>(outF, FFt);
    k_lu<<<1, 64, 0, stream>>>(SDS, GP, scal);
    k_final<<<1, 256, 0, stream>>>(GP, SS, FFt, u_vec, sizes, deg64, AS64, outS, scal, outL, (float)n);
}